// Round 6
// baseline (2871.712 us; speedup 1.0000x reference)
//
#include <hip/hip_runtime.h>

#define NN 50000
#define NH 100000
#define NI 600000
#define FIN 512
#define HID 128
#define LNEPS 1e-5f

static __device__ __forceinline__ void fma4(float4& a, float s, const float4& w) {
  a.x += s * w.x; a.y += s * w.y; a.z += s * w.z; a.w += s * w.w;
}

// ============================ CSR build ============================
__global__ void k_hist(const int* __restrict__ idx, int n, int* __restrict__ deg) {
  int i = blockIdx.x * 256 + threadIdx.x;
  if (i < n) atomicAdd(&deg[idx[i]], 1);
}

__global__ __launch_bounds__(1024) void k_scan1(int* __restrict__ data, int m,
                                                int* __restrict__ bsums) {
  __shared__ int sh[1024];
  int tid = threadIdx.x;
  int i = blockIdx.x * 1024 + tid;
  int v = (i < m) ? data[i] : 0;
  sh[tid] = v;
  __syncthreads();
  for (int off = 1; off < 1024; off <<= 1) {
    int tv = (tid >= off) ? sh[tid - off] : 0;
    __syncthreads();
    sh[tid] += tv;
    __syncthreads();
  }
  if (i < m) data[i] = sh[tid] - v;  // exclusive
  if (tid == 1023) bsums[blockIdx.x] = sh[1023];
}

__global__ __launch_bounds__(1024) void k_scan2(int* __restrict__ bsums, int nb) {
  __shared__ int sh[1024];
  int tid = threadIdx.x;
  int v = (tid < nb) ? bsums[tid] : 0;
  sh[tid] = v;
  __syncthreads();
  for (int off = 1; off < 1024; off <<= 1) {
    int tv = (tid >= off) ? sh[tid - off] : 0;
    __syncthreads();
    sh[tid] += tv;
    __syncthreads();
  }
  if (tid < nb) bsums[tid] = sh[tid] - v;
}

__global__ void k_scan3(int* __restrict__ data, const int* __restrict__ bsums,
                        int m, int total) {
  int i = blockIdx.x * 256 + threadIdx.x;
  if (i < m) data[i] += bsums[i >> 10];
  if (i == 0) data[m] = total;
}

__global__ void k_fill(const int* __restrict__ key, const int* __restrict__ oth, int n,
                       const int* __restrict__ starts, int* __restrict__ cursor,
                       int* __restrict__ out_oth) {
  int i = blockIdx.x * 256 + threadIdx.x;
  if (i >= n) return;
  int k = key[i];
  int pos = starts[k] + atomicAdd(&cursor[k], 1);
  out_oth[pos] = oth[i];
}

// Sort each CSR segment ascending -> deterministic order every replay.
__global__ void k_sort_seg(const int* __restrict__ starts, int nseg,
                           int* __restrict__ vals) {
  int seg = blockIdx.x * 256 + threadIdx.x;
  if (seg >= nseg) return;
  int s = starts[seg], e = starts[seg + 1];
  int d = e - s;
  if (d <= 1) return;
  if (d <= 48) {
    int buf[48];
    for (int i = 0; i < d; i++) buf[i] = vals[s + i];
    for (int i = 1; i < d; i++) {
      int key = buf[i], j = i - 1;
      while (j >= 0 && buf[j] > key) { buf[j + 1] = buf[j]; j--; }
      buf[j + 1] = key;
    }
    for (int i = 0; i < d; i++) vals[s + i] = buf[i];
  } else {
    for (int i = s + 1; i < e; i++) {
      int key = vals[i], j = i - 1;
      while (j >= s && vals[j] > key) { vals[j + 1] = vals[j]; j--; }
      vals[j + 1] = key;
    }
  }
}

// ============================ W2 precompute ============================
__global__ void k_prep_w2g(const float* __restrict__ W2, const float* __restrict__ g2,
                           float* __restrict__ W2g) {
  int i = blockIdx.x * 256 + threadIdx.x;
  if (i >= 256 * 128) return;
  int k = i >> 7;
  W2g[i] = g2[k] * W2[i];
}

__global__ __launch_bounds__(128) void k_prep_sgc0(
    const float* __restrict__ W2, const float* __restrict__ g2,
    const float* __restrict__ b2, const float* __restrict__ bias2,
    float* __restrict__ s_g, float* __restrict__ c0) {
  int t = threadIdx.x;
  float sg = 0.f, cc = 0.f;
  for (int k = 0; k < 256; k++) {
    float w = W2[k * 128 + t];
    sg += g2[k] * w;
    cc += b2[k] * w;
  }
  s_g[t] = sg;
  c0[t] = cc + bias2[t];
}

// ============================ shared GEMM core ============================
// Ash: 32x128 fp32 tile (stride 132). Wsh: 128x64 col-half (stride 68).
// Thread (tc=t&15, tr=t>>4) computes rows tr*2..+1, cols tc*4..+3 per half.
static __device__ __forceinline__ void gemm_inner(
    const float (*Ash)[132], const float (*Wsh)[68], int tc, int tr,
    float4& acc0, float4& acc1) {
#pragma unroll 8
  for (int k = 0; k < 128; k += 4) {
    float4 w0 = *(const float4*)&Wsh[k + 0][tc * 4];
    float4 w1 = *(const float4*)&Wsh[k + 1][tc * 4];
    float4 w2 = *(const float4*)&Wsh[k + 2][tc * 4];
    float4 w3 = *(const float4*)&Wsh[k + 3][tc * 4];
    float4 a0 = *(const float4*)&Ash[tr * 2 + 0][k];
    float4 a1 = *(const float4*)&Ash[tr * 2 + 1][k];
    fma4(acc0, a0.x, w0); fma4(acc0, a0.y, w1); fma4(acc0, a0.z, w2); fma4(acc0, a0.w, w3);
    fma4(acc1, a1.x, w0); fma4(acc1, a1.y, w1); fma4(acc1, a1.z, w2); fma4(acc1, a1.w, w3);
  }
}

template <bool BIAS, bool RELU>
static __device__ __forceinline__ void tile_gemm_out(
    const float (*Ash)[132], float (*Wsh)[68], const float* __restrict__ W,
    const float* __restrict__ bias, float* __restrict__ out, int r0, int N, int t) {
  const int tc = t & 15, tr = t >> 4;
  for (int ch = 0; ch < 2; ch++) {
    __syncthreads();  // Ash writers / previous-phase Wsh readers done
    for (int s = t; s < 2048; s += 256) {
      int k = s >> 4, c4 = (s & 15) * 4;
      *(float4*)&Wsh[k][c4] = *(const float4*)(W + (size_t)k * 128 + ch * 64 + c4);
    }
    __syncthreads();
    float4 acc0 = {0, 0, 0, 0}, acc1 = {0, 0, 0, 0};
    gemm_inner(Ash, (const float(*)[68])Wsh, tc, tr, acc0, acc1);
    int c = ch * 64 + tc * 4;
    float4 bb = {0, 0, 0, 0};
    if (BIAS) bb = *(const float4*)(bias + c);
    int row0 = r0 + tr * 2;
    if (row0 < N) {
      float4 o;
      o.x = acc0.x + bb.x; o.y = acc0.y + bb.y; o.z = acc0.z + bb.z; o.w = acc0.w + bb.w;
      if (RELU) { o.x = fmaxf(o.x, 0.f); o.y = fmaxf(o.y, 0.f); o.z = fmaxf(o.z, 0.f); o.w = fmaxf(o.w, 0.f); }
      *(float4*)(out + (size_t)row0 * 128 + c) = o;
    }
    if (row0 + 1 < N) {
      float4 o;
      o.x = acc1.x + bb.x; o.y = acc1.y + bb.y; o.z = acc1.z + bb.z; o.w = acc1.w + bb.w;
      if (RELU) { o.x = fmaxf(o.x, 0.f); o.y = fmaxf(o.y, 0.f); o.z = fmaxf(o.z, 0.f); o.w = fmaxf(o.w, 0.f); }
      *(float4*)(out + (size_t)(row0 + 1) * 128 + c) = o;
    }
  }
}

// ============================ K=128 GEMM (optional fused LN+stats) ============================
template <bool LN, bool BIAS, bool RELU>
__global__ __launch_bounds__(256) void k_tile128(
    const float* __restrict__ A, const float* __restrict__ W,
    const float* __restrict__ bias, const float* __restrict__ lng,
    const float* __restrict__ lnb, float* __restrict__ sn,
    float* __restrict__ qn, float* __restrict__ out, int N) {
  __shared__ float Ash[32][132];
  __shared__ float Wsh[128][68];
  const int t = threadIdx.x;
  const int r0 = blockIdx.x * 32;
  for (int s = t; s < 1024; s += 256) {
    int r = s >> 5, c4 = (s & 31) * 4;
    float4 val = {0, 0, 0, 0};
    if (r0 + r < N) val = *(const float4*)(A + (size_t)(r0 + r) * 128 + c4);
    *(float4*)&Ash[r][c4] = val;
  }
  if (LN) {
    __syncthreads();
    int wv = t >> 6, lane = t & 63;
    // 4 waves x 8 rows = 32-row tile
    for (int j = 0; j < 8; j++) {
      int r = wv * 8 + j;
      if (r0 + r < N) {
        float2 x = *(float2*)&Ash[r][lane * 2];
        float s = x.x + x.y, sq = x.x * x.x + x.y * x.y;
        for (int m = 1; m < 64; m <<= 1) { s += __shfl_xor(s, m); sq += __shfl_xor(sq, m); }
        if (lane == 0) { sn[r0 + r] = s; qn[r0 + r] = sq; }
        float mu = s * (1.f / 128.f);
        float var = sq * (1.f / 128.f) - mu * mu;
        float rstd = rsqrtf(var + LNEPS);
        float2 gg = ((const float2*)lng)[lane];
        float2 bb = ((const float2*)lnb)[lane];
        float2 o;
        o.x = (x.x - mu) * rstd * gg.x + bb.x;
        o.y = (x.y - mu) * rstd * gg.y + bb.y;
        *(float2*)&Ash[r][lane * 2] = o;
      }
    }
  }
  tile_gemm_out<BIAS, RELU>((const float(*)[132])Ash, Wsh, W, bias, out, r0, N, t);
}

// ============================ input projection K=512 ============================
__global__ __launch_bounds__(256) void k_proj(
    const float* __restrict__ A, const float* __restrict__ W,
    const float* __restrict__ bias, float* __restrict__ out,
    float* __restrict__ out2, int N) {
  __shared__ float Ash[32][132];
  __shared__ float Wsh[128][68];
  const int t = threadIdx.x;
  const int r0 = blockIdx.x * 32;
  const int tc = t & 15, tr = t >> 4;
  for (int ch = 0; ch < 2; ch++) {
    float4 acc0 = {0, 0, 0, 0}, acc1 = {0, 0, 0, 0};
    for (int kc = 0; kc < 4; kc++) {
      __syncthreads();
      for (int s = t; s < 1024; s += 256) {
        int r = s >> 5, c4 = (s & 31) * 4;
        float4 val = {0, 0, 0, 0};
        if (r0 + r < N) val = *(const float4*)(A + (size_t)(r0 + r) * 512 + kc * 128 + c4);
        *(float4*)&Ash[r][c4] = val;
      }
      for (int s = t; s < 2048; s += 256) {
        int k = s >> 4, c4 = (s & 15) * 4;
        *(float4*)&Wsh[k][c4] = *(const float4*)(W + (size_t)(kc * 128 + k) * 128 + ch * 64 + c4);
      }
      __syncthreads();
      gemm_inner((const float(*)[132])Ash, (const float(*)[68])Wsh, tc, tr, acc0, acc1);
    }
    int c = ch * 64 + tc * 4;
    float4 bb = *(const float4*)(bias + c);
    int row0 = r0 + tr * 2;
    if (row0 < N) {
      float4 o;
      o.x = fmaxf(acc0.x + bb.x, 0.f); o.y = fmaxf(acc0.y + bb.y, 0.f);
      o.z = fmaxf(acc0.z + bb.z, 0.f); o.w = fmaxf(acc0.w + bb.w, 0.f);
      *(float4*)(out + (size_t)row0 * 128 + c) = o;
      *(float4*)(out2 + (size_t)row0 * 128 + c) = o;
    }
    if (row0 + 1 < N) {
      float4 o;
      o.x = fmaxf(acc1.x + bb.x, 0.f); o.y = fmaxf(acc1.y + bb.y, 0.f);
      o.z = fmaxf(acc1.z + bb.z, 0.f); o.w = fmaxf(acc1.w + bb.w, 0.f);
      *(float4*)(out + (size_t)(row0 + 1) * 128 + c) = o;
      *(float4*)(out2 + (size_t)(row0 + 1) * 128 + c) = o;
    }
  }
}

// ============================ fused hedge-mean + stats + V-GEMM ============================
__global__ __launch_bounds__(256) void k_xe_v(
    const float* __restrict__ B, const int* __restrict__ starts,
    const int* __restrict__ vlist, const float* __restrict__ Wv,
    float* __restrict__ V, float* __restrict__ se, float* __restrict__ qe) {
  __shared__ float Ash[32][132];
  __shared__ float Wsh[128][68];
  const int t = threadIdx.x;
  const int h0 = blockIdx.x * 32;
  const int wv = t >> 6, lane = t & 63;
  // 4 waves x 8 rows = 32-row tile
  for (int j = 0; j < 8; j++) {
    int row = wv * 8 + j;
    int m = h0 + row;
    int s = starts[m], e = starts[m + 1];
    float2 acc = {0.f, 0.f};
    for (int jj = s; jj < e; jj++) {
      int vv = vlist[jj];
      float2 val = ((const float2*)(B + (size_t)vv * 128))[lane];
      acc.x += val.x; acc.y += val.y;
    }
    int d = e - s;
    float inv = d > 0 ? 1.f / (float)d : 0.f;
    float2 o = {acc.x * inv, acc.y * inv};
    *(float2*)&Ash[row][lane * 2] = o;
    float ss = o.x + o.y, qq = o.x * o.x + o.y * o.y;
    for (int mm = 1; mm < 64; mm <<= 1) { ss += __shfl_xor(ss, mm); qq += __shfl_xor(qq, mm); }
    if (lane == 0) { se[m] = ss; qe[m] = qq; }
  }
  tile_gemm_out<false, false>((const float(*)[132])Ash, Wsh, Wv, nullptr, V, h0, NH, t);
}

// ============================ fused node-combine + blend + LN + W-GEMM + relu ============================
__global__ __launch_bounds__(256) void k_node_w(
    const float* __restrict__ U, const float* __restrict__ V,
    const float* __restrict__ X0, const int* __restrict__ starts_v,
    const int* __restrict__ e_by_v, const float* __restrict__ sn,
    const float* __restrict__ qn, const float* __restrict__ se,
    const float* __restrict__ qe, const float* __restrict__ s_g,
    const float* __restrict__ c0, const float* __restrict__ wg,
    const float* __restrict__ wbn, const float* __restrict__ Ww,
    const float* __restrict__ wb, float* __restrict__ Xout, int N) {
  __shared__ float Ash[32][132];
  __shared__ float Wsh[128][68];
  const int t = threadIdx.x;
  const int v0 = blockIdx.x * 32;
  const int wv = t >> 6, lane = t & 63;
  // 4 waves x 8 rows = 32-row tile
  for (int j = 0; j < 8; j++) {
    int row = wv * 8 + j;
    int v = v0 + row;
    float2 o = {0.f, 0.f};
    if (v < N) {
      int s = starts_v[v], e = starts_v[v + 1];
      float svn = sn[v], qvn = qn[v];
      float2 acc = {0.f, 0.f};
      float suma = 0.f, sumb = 0.f;
      for (int jj = s; jj < e; jj++) {
        int ee = e_by_v[jj];
        float mu = (svn + se[ee]) * (1.f / 256.f);
        float e2 = (qvn + qe[ee]) * (1.f / 256.f);
        float rstd = rsqrtf(e2 - mu * mu + LNEPS);
        suma += rstd;
        sumb += mu * rstd;
        float2 vvv = ((const float2*)(V + (size_t)ee * 128))[lane];
        acc.x += rstd * vvv.x;
        acc.y += rstd * vvv.y;
      }
      int deg = e - s;
      float inv = deg > 0 ? 1.f / (float)deg : 0.f;
      float2 uu = ((const float2*)(U + (size_t)v * 128))[lane];
      float2 sg = ((const float2*)s_g)[lane];
      float2 cc = ((const float2*)c0)[lane];
      float xvx = deg > 0 ? (suma * uu.x + acc.x - sumb * sg.x) * inv + cc.x : 0.f;
      float xvy = deg > 0 ? (suma * uu.y + acc.y - sumb * sg.y) * inv + cc.y : 0.f;
      float2 x0 = ((const float2*)(X0 + (size_t)v * 128))[lane];
      float ax = 0.5f * xvx + 0.5f * x0.x;
      float ay = 0.5f * xvy + 0.5f * x0.y;
      float ss = ax + ay, qq = ax * ax + ay * ay;
      for (int m = 1; m < 64; m <<= 1) { ss += __shfl_xor(ss, m); qq += __shfl_xor(qq, m); }
      float mu = ss * (1.f / 128.f);
      float var = qq * (1.f / 128.f) - mu * mu;
      float rstd = rsqrtf(var + LNEPS);
      float2 gg = ((const float2*)wg)[lane];
      float2 bb = ((const float2*)wbn)[lane];
      o.x = (ax - mu) * rstd * gg.x + bb.x;
      o.y = (ay - mu) * rstd * gg.y + bb.y;
    }
    *(float2*)&Ash[row][lane * 2] = o;
  }
  tile_gemm_out<true, true>((const float(*)[132])Ash, Wsh, Ww, wb, Xout, v0, N, t);
}

// ============================ classifier ============================
__global__ __launch_bounds__(128) void k_cls(
    const float* __restrict__ X, const float* __restrict__ W1,
    const float* __restrict__ b1, const float* __restrict__ lg,
    const float* __restrict__ lb, const float* __restrict__ W2,
    const float* __restrict__ b2, float* __restrict__ out, int N) {
  __shared__ float xr[128];
  int n = blockIdx.x, t = threadIdx.x;
  xr[t] = X[(size_t)n * 128 + t];
  __syncthreads();
  if (t < 64) {
    float a = b1[t];
    for (int k = 0; k < 128; k++) a += xr[k] * W1[k * 64 + t];
    float h = fmaxf(a, 0.f);
    float s = h, sq = h * h;
    for (int m = 1; m < 64; m <<= 1) { s += __shfl_xor(s, m); sq += __shfl_xor(sq, m); }
    float mu = s * (1.f / 64.f);
    float var = sq * (1.f / 64.f) - mu * mu;
    float rstd = rsqrtf(var + LNEPS);
    float hn = (h - mu) * rstd * lg[t] + lb[t];
    float c = hn * W2[t];
    for (int m = 1; m < 64; m <<= 1) c += __shfl_xor(c, m);
    if (t == 0) out[n] = c + b2[0];
  }
}

// ============================ driver ============================
static void run_branch(const float* x_in, const int* v, const int* e,
                       const float* lin_w, const float* lin_b,
                       const float* w1g, const float* w1bn, const float* w1w, const float* w1b,
                       const float* W2g, const float* s_g, const float* c0,
                       const float* wg, const float* wbn, const float* ww, const float* wb,
                       const float* cw1, const float* cb1, const float* cg, const float* cbn,
                       const float* cw2, const float* cb2,
                       float* X, float* X0, float* B, float* Xe,
                       float* sn, float* qn, float* se, float* qe,
                       int* starts_e, int* starts_v, int* cursor, int* bsums,
                       int* v_by_e, int* e_by_v,
                       float* out, hipStream_t stream) {
  const int GN = (NN + 31) / 32;   // 1563
  const int GH = NH / 32;          // 3125
  // CSR by hedge
  hipMemsetAsync(starts_e, 0, (NH + 1) * sizeof(int), stream);
  k_hist<<<(NI + 255) / 256, 256, 0, stream>>>(e, NI, starts_e);
  k_scan1<<<(NH + 1023) / 1024, 1024, 0, stream>>>(starts_e, NH, bsums);
  k_scan2<<<1, 1024, 0, stream>>>(bsums, (NH + 1023) / 1024);
  k_scan3<<<(NH + 255) / 256, 256, 0, stream>>>(starts_e, bsums, NH, NI);
  hipMemsetAsync(cursor, 0, NH * sizeof(int), stream);
  k_fill<<<(NI + 255) / 256, 256, 0, stream>>>(e, v, NI, starts_e, cursor, v_by_e);
  k_sort_seg<<<(NH + 255) / 256, 256, 0, stream>>>(starts_e, NH, v_by_e);
  // CSR by node
  hipMemsetAsync(starts_v, 0, (NN + 1) * sizeof(int), stream);
  k_hist<<<(NI + 255) / 256, 256, 0, stream>>>(v, NI, starts_v);
  k_scan1<<<(NN + 1023) / 1024, 1024, 0, stream>>>(starts_v, NN, bsums);
  k_scan2<<<1, 1024, 0, stream>>>(bsums, (NN + 1023) / 1024);
  k_scan3<<<(NN + 255) / 256, 256, 0, stream>>>(starts_v, bsums, NN, NI);
  hipMemsetAsync(cursor, 0, NN * sizeof(int), stream);
  k_fill<<<(NI + 255) / 256, 256, 0, stream>>>(v, e, NI, starts_v, cursor, e_by_v);
  k_sort_seg<<<(NN + 255) / 256, 256, 0, stream>>>(starts_v, NN, e_by_v);
  // input projection (+relu), duplicated into X and X0
  k_proj<<<GN, 256, 0, stream>>>(x_in, lin_w, lin_b, X, X0, NN);
  for (int layer = 0; layer < 2; ++layer) {
    // B = LN(X; w1g,w1bn) @ W1 + b1 ; also emit raw row stats sn,qn of X
    k_tile128<true, true, false><<<GN, 256, 0, stream>>>(
        X, w1w, w1b, w1g, w1bn, sn, qn, B, NN);
    // U = X @ W2g_top  (in-place over X)
    k_tile128<false, false, false><<<GN, 256, 0, stream>>>(
        X, W2g, nullptr, nullptr, nullptr, nullptr, nullptr, X, NN);
    // V = mean_e(B) @ W2g_bot ; emit se,qe stats of the means
    k_xe_v<<<GH, 256, 0, stream>>>(B, starts_e, v_by_e, W2g + 128 * 128, Xe, se, qe);
    // X = relu( LN(0.5*Xv + 0.5*X0) @ Ww + wb )  (in-place over U)
    k_node_w<<<GN, 256, 0, stream>>>(X, Xe, X0, starts_v, e_by_v, sn, qn, se, qe,
                                     s_g, c0, wg, wbn, ww, wb, X, NN);
  }
  k_cls<<<NN, 128, 0, stream>>>(X, cw1, cb1, cg, cbn, cw2, cb2, out, NN);
}

extern "C" void kernel_launch(void* const* d_in, const int* in_sizes, int n_in,
                              void* d_out, int out_size, void* d_ws, size_t ws_size,
                              hipStream_t stream) {
  (void)in_sizes; (void)n_in; (void)out_size; (void)ws_size;
  const float* x1 = (const float*)d_in[0];
  const int* v1 = (const int*)d_in[1];
  const int* e1 = (const int*)d_in[2];
  const float* x2 = (const float*)d_in[3];
  const int* v2 = (const int*)d_in[4];
  const int* e2 = (const int*)d_in[5];
  const float* lin_w = (const float*)d_in[6];
  const float* lin_b = (const float*)d_in[7];
  const float* w1g = (const float*)d_in[8];
  const float* w1bn = (const float*)d_in[9];
  const float* w1w = (const float*)d_in[10];
  const float* w1b = (const float*)d_in[11];
  const float* w2g = (const float*)d_in[12];
  const float* w2bn = (const float*)d_in[13];
  const float* w2w = (const float*)d_in[14];
  const float* w2b = (const float*)d_in[15];
  const float* wg = (const float*)d_in[16];
  const float* wbn = (const float*)d_in[17];
  const float* ww = (const float*)d_in[18];
  const float* wb = (const float*)d_in[19];
  const float* cw1 = (const float*)d_in[20];
  const float* cb1 = (const float*)d_in[21];
  const float* cg = (const float*)d_in[22];
  const float* cbn = (const float*)d_in[23];
  const float* cw2 = (const float*)d_in[24];
  const float* cb2 = (const float*)d_in[25];

  char* p = (char*)d_ws;
  auto alloc = [&](size_t bytes) {
    char* r = p;
    p += (bytes + 255) & ~(size_t)255;
    return r;
  };
  float* X = (float*)alloc((size_t)NN * 128 * 4);   // X / U / next-X (in-place)
  float* X0 = (float*)alloc((size_t)NN * 128 * 4);
  float* B = (float*)alloc((size_t)NN * 128 * 4);
  float* Xe = (float*)alloc((size_t)NH * 128 * 4);  // V
  float* sn = (float*)alloc((size_t)NN * 4);
  float* qn = (float*)alloc((size_t)NN * 4);
  float* se = (float*)alloc((size_t)NH * 4);
  float* qe = (float*)alloc((size_t)NH * 4);
  int* starts_e = (int*)alloc((NH + 1) * 4);
  int* starts_v = (int*)alloc((NN + 1) * 4);
  int* cursor = (int*)alloc(NH * 4);
  int* bsums = (int*)alloc(1024 * 4);
  int* v_by_e = (int*)alloc((size_t)NI * 4);
  int* e_by_v = (int*)alloc((size_t)NI * 4);
  float* W2g = (float*)alloc((size_t)256 * 128 * 4);
  float* s_g = (float*)alloc(128 * 4);
  float* c0 = (float*)alloc(128 * 4);

  // one-time per launch: W2 precomputation (shared by both branches)
  k_prep_w2g<<<128, 256, 0, stream>>>(w2w, w2g, W2g);
  k_prep_sgc0<<<1, 128, 0, stream>>>(w2w, w2g, w2bn, w2b, s_g, c0);

  float* out = (float*)d_out;
  run_branch(x1, v1, e1, lin_w, lin_b, w1g, w1bn, w1w, w1b, W2g, s_g, c0,
             wg, wbn, ww, wb, cw1, cb1, cg, cbn, cw2, cb2,
             X, X0, B, Xe, sn, qn, se, qe, starts_e, starts_v, cursor, bsums,
             v_by_e, e_by_v, out, stream);
  run_branch(x2, v2, e2, lin_w, lin_b, w1g, w1bn, w1w, w1b, W2g, s_g, c0,
             wg, wbn, ww, wb, cw1, cb1, cg, cbn, cw2, cb2,
             X, X0, B, Xe, sn, qn, se, qe, starts_e, starts_v, cursor, bsums,
             v_by_e, e_by_v, out + NN, stream);
}

// Round 7
// 2022.172 us; speedup vs baseline: 1.4201x; 1.4201x over previous
//
#include <hip/hip_runtime.h>

#define NN 50000
#define NH 100000
#define NI 600000
#define FIN 512
#define HID 128
#define LNEPS 1e-5f

static __device__ __forceinline__ void fma4(float4& a, float s, const float4& w) {
  a.x += s * w.x; a.y += s * w.y; a.z += s * w.z; a.w += s * w.w;
}

// ============================ CSR build ============================
__global__ void k_hist(const int* __restrict__ idx, int n, int* __restrict__ deg) {
  int i = blockIdx.x * 256 + threadIdx.x;
  if (i < n) atomicAdd(&deg[idx[i]], 1);
}

__global__ __launch_bounds__(1024) void k_scan1(int* __restrict__ data, int m,
                                                int* __restrict__ bsums) {
  __shared__ int sh[1024];
  int tid = threadIdx.x;
  int i = blockIdx.x * 1024 + tid;
  int v = (i < m) ? data[i] : 0;
  sh[tid] = v;
  __syncthreads();
  for (int off = 1; off < 1024; off <<= 1) {
    int tv = (tid >= off) ? sh[tid - off] : 0;
    __syncthreads();
    sh[tid] += tv;
    __syncthreads();
  }
  if (i < m) data[i] = sh[tid] - v;  // exclusive
  if (tid == 1023) bsums[blockIdx.x] = sh[1023];
}

__global__ __launch_bounds__(1024) void k_scan2(int* __restrict__ bsums, int nb) {
  __shared__ int sh[1024];
  int tid = threadIdx.x;
  int v = (tid < nb) ? bsums[tid] : 0;
  sh[tid] = v;
  __syncthreads();
  for (int off = 1; off < 1024; off <<= 1) {
    int tv = (tid >= off) ? sh[tid - off] : 0;
    __syncthreads();
    sh[tid] += tv;
    __syncthreads();
  }
  if (tid < nb) bsums[tid] = sh[tid] - v;
}

__global__ void k_scan3(int* __restrict__ data, const int* __restrict__ bsums,
                        int m, int total) {
  int i = blockIdx.x * 256 + threadIdx.x;
  if (i < m) data[i] += bsums[i >> 10];
  if (i == 0) data[m] = total;
}

__global__ void k_fill(const int* __restrict__ key, const int* __restrict__ oth, int n,
                       const int* __restrict__ starts, int* __restrict__ cursor,
                       int* __restrict__ out_oth) {
  int i = blockIdx.x * 256 + threadIdx.x;
  if (i >= n) return;
  int k = key[i];
  int pos = starts[k] + atomicAdd(&cursor[k], 1);
  out_oth[pos] = oth[i];
}

// Sort each CSR segment ascending -> deterministic order every replay.
__global__ void k_sort_seg(const int* __restrict__ starts, int nseg,
                           int* __restrict__ vals) {
  int seg = blockIdx.x * 256 + threadIdx.x;
  if (seg >= nseg) return;
  int s = starts[seg], e = starts[seg + 1];
  int d = e - s;
  if (d <= 1) return;
  if (d <= 48) {
    int buf[48];
    for (int i = 0; i < d; i++) buf[i] = vals[s + i];
    for (int i = 1; i < d; i++) {
      int key = buf[i], j = i - 1;
      while (j >= 0 && buf[j] > key) { buf[j + 1] = buf[j]; j--; }
      buf[j + 1] = key;
    }
    for (int i = 0; i < d; i++) vals[s + i] = buf[i];
  } else {
    for (int i = s + 1; i < e; i++) {
      int key = vals[i], j = i - 1;
      while (j >= s && vals[j] > key) { vals[j + 1] = vals[j]; j--; }
      vals[j + 1] = key;
    }
  }
}

// ============================ W2 precompute ============================
__global__ void k_prep_w2g(const float* __restrict__ W2, const float* __restrict__ g2,
                           float* __restrict__ W2g) {
  int i = blockIdx.x * 256 + threadIdx.x;
  if (i >= 256 * 128) return;
  int k = i >> 7;
  W2g[i] = g2[k] * W2[i];
}

__global__ __launch_bounds__(128) void k_prep_sgc0(
    const float* __restrict__ W2, const float* __restrict__ g2,
    const float* __restrict__ b2, const float* __restrict__ bias2,
    float* __restrict__ s_g, float* __restrict__ c0) {
  int t = threadIdx.x;
  float sg = 0.f, cc = 0.f;
  for (int k = 0; k < 256; k++) {
    float w = W2[k * 128 + t];
    sg += g2[k] * w;
    cc += b2[k] * w;
  }
  s_g[t] = sg;
  c0[t] = cc + bias2[t];
}

// ============================ shared GEMM core (K=128) ============================
static __device__ __forceinline__ void gemm_inner(
    const float (*Ash)[132], const float (*Wsh)[68], int tc, int tr,
    float4& acc0, float4& acc1) {
#pragma unroll 8
  for (int k = 0; k < 128; k += 4) {
    float4 w0 = *(const float4*)&Wsh[k + 0][tc * 4];
    float4 w1 = *(const float4*)&Wsh[k + 1][tc * 4];
    float4 w2 = *(const float4*)&Wsh[k + 2][tc * 4];
    float4 w3 = *(const float4*)&Wsh[k + 3][tc * 4];
    float4 a0 = *(const float4*)&Ash[tr * 2 + 0][k];
    float4 a1 = *(const float4*)&Ash[tr * 2 + 1][k];
    fma4(acc0, a0.x, w0); fma4(acc0, a0.y, w1); fma4(acc0, a0.z, w2); fma4(acc0, a0.w, w3);
    fma4(acc1, a1.x, w0); fma4(acc1, a1.y, w1); fma4(acc1, a1.z, w2); fma4(acc1, a1.w, w3);
  }
}

template <bool BIAS, bool RELU>
static __device__ __forceinline__ void tile_gemm_out(
    const float (*Ash)[132], float (*Wsh)[68], const float* __restrict__ W,
    const float* __restrict__ bias, float* __restrict__ out, int r0, int N, int t) {
  const int tc = t & 15, tr = t >> 4;
  for (int ch = 0; ch < 2; ch++) {
    __syncthreads();
    for (int s = t; s < 2048; s += 256) {
      int k = s >> 4, c4 = (s & 15) * 4;
      *(float4*)&Wsh[k][c4] = *(const float4*)(W + (size_t)k * 128 + ch * 64 + c4);
    }
    __syncthreads();
    float4 acc0 = {0, 0, 0, 0}, acc1 = {0, 0, 0, 0};
    gemm_inner(Ash, (const float(*)[68])Wsh, tc, tr, acc0, acc1);
    int c = ch * 64 + tc * 4;
    float4 bb = {0, 0, 0, 0};
    if (BIAS) bb = *(const float4*)(bias + c);
    int row0 = r0 + tr * 2;
    if (row0 < N) {
      float4 o;
      o.x = acc0.x + bb.x; o.y = acc0.y + bb.y; o.z = acc0.z + bb.z; o.w = acc0.w + bb.w;
      if (RELU) { o.x = fmaxf(o.x, 0.f); o.y = fmaxf(o.y, 0.f); o.z = fmaxf(o.z, 0.f); o.w = fmaxf(o.w, 0.f); }
      *(float4*)(out + (size_t)row0 * 128 + c) = o;
    }
    if (row0 + 1 < N) {
      float4 o;
      o.x = acc1.x + bb.x; o.y = acc1.y + bb.y; o.z = acc1.z + bb.z; o.w = acc1.w + bb.w;
      if (RELU) { o.x = fmaxf(o.x, 0.f); o.y = fmaxf(o.y, 0.f); o.z = fmaxf(o.z, 0.f); o.w = fmaxf(o.w, 0.f); }
      *(float4*)(out + (size_t)(row0 + 1) * 128 + c) = o;
    }
  }
}

// ============================ K=128 GEMM (optional fused LN+stats) ============================
template <bool LN, bool BIAS, bool RELU>
__global__ __launch_bounds__(256) void k_tile128(
    const float* __restrict__ A, const float* __restrict__ W,
    const float* __restrict__ bias, const float* __restrict__ lng,
    const float* __restrict__ lnb, float* __restrict__ sn,
    float* __restrict__ qn, float* __restrict__ out, int N) {
  __shared__ float Ash[32][132];
  __shared__ float Wsh[128][68];
  const int t = threadIdx.x;
  const int r0 = blockIdx.x * 32;
  for (int s = t; s < 1024; s += 256) {
    int r = s >> 5, c4 = (s & 31) * 4;
    float4 val = {0, 0, 0, 0};
    if (r0 + r < N) val = *(const float4*)(A + (size_t)(r0 + r) * 128 + c4);
    *(float4*)&Ash[r][c4] = val;
  }
  if (LN) {
    __syncthreads();
    int wv = t >> 6, lane = t & 63;
    for (int j = 0; j < 8; j++) {
      int r = wv * 8 + j;
      if (r0 + r < N) {
        float2 x = *(float2*)&Ash[r][lane * 2];
        float s = x.x + x.y, sq = x.x * x.x + x.y * x.y;
        for (int m = 1; m < 64; m <<= 1) { s += __shfl_xor(s, m); sq += __shfl_xor(sq, m); }
        if (lane == 0) { sn[r0 + r] = s; qn[r0 + r] = sq; }
        float mu = s * (1.f / 128.f);
        float var = sq * (1.f / 128.f) - mu * mu;
        float rstd = rsqrtf(var + LNEPS);
        float2 gg = ((const float2*)lng)[lane];
        float2 bb = ((const float2*)lnb)[lane];
        float2 o;
        o.x = (x.x - mu) * rstd * gg.x + bb.x;
        o.y = (x.y - mu) * rstd * gg.y + bb.y;
        *(float2*)&Ash[r][lane * 2] = o;
      }
    }
  }
  tile_gemm_out<BIAS, RELU>((const float(*)[132])Ash, Wsh, W, bias, out, r0, N, t);
}

// ============================ input projection K=512 ============================
__global__ __launch_bounds__(256) void k_proj(
    const float* __restrict__ A, const float* __restrict__ W,
    const float* __restrict__ bias, float* __restrict__ out,
    float* __restrict__ out2, int N) {
  __shared__ float Ash[32][132];
  __shared__ float Wsh[128][68];
  const int t = threadIdx.x;
  const int r0 = blockIdx.x * 32;
  const int tc = t & 15, tr = t >> 4;
  for (int ch = 0; ch < 2; ch++) {
    float4 acc0 = {0, 0, 0, 0}, acc1 = {0, 0, 0, 0};
    for (int kc = 0; kc < 4; kc++) {
      __syncthreads();
      for (int s = t; s < 1024; s += 256) {
        int r = s >> 5, c4 = (s & 31) * 4;
        float4 val = {0, 0, 0, 0};
        if (r0 + r < N) val = *(const float4*)(A + (size_t)(r0 + r) * 512 + kc * 128 + c4);
        *(float4*)&Ash[r][c4] = val;
      }
      for (int s = t; s < 2048; s += 256) {
        int k = s >> 4, c4 = (s & 15) * 4;
        *(float4*)&Wsh[k][c4] = *(const float4*)(W + (size_t)(kc * 128 + k) * 128 + ch * 64 + c4);
      }
      __syncthreads();
      gemm_inner((const float(*)[132])Ash, (const float(*)[68])Wsh, tc, tr, acc0, acc1);
    }
    int c = ch * 64 + tc * 4;
    float4 bb = *(const float4*)(bias + c);
    int row0 = r0 + tr * 2;
    if (row0 < N) {
      float4 o;
      o.x = fmaxf(acc0.x + bb.x, 0.f); o.y = fmaxf(acc0.y + bb.y, 0.f);
      o.z = fmaxf(acc0.z + bb.z, 0.f); o.w = fmaxf(acc0.w + bb.w, 0.f);
      *(float4*)(out + (size_t)row0 * 128 + c) = o;
      *(float4*)(out2 + (size_t)row0 * 128 + c) = o;
    }
    if (row0 + 1 < N) {
      float4 o;
      o.x = fmaxf(acc1.x + bb.x, 0.f); o.y = fmaxf(acc1.y + bb.y, 0.f);
      o.z = fmaxf(acc1.z + bb.z, 0.f); o.w = fmaxf(acc1.w + bb.w, 0.f);
      *(float4*)(out + (size_t)(row0 + 1) * 128 + c) = o;
      *(float4*)(out2 + (size_t)(row0 + 1) * 128 + c) = o;
    }
  }
}

// ============================ hedge mean gather (half-wave per hedge) ============================
__global__ __launch_bounds__(256) void k_xe(
    const float* __restrict__ B, const int* __restrict__ starts,
    const int* __restrict__ vlist, float* __restrict__ Xe,
    float* __restrict__ se, float* __restrict__ qe, int M) {
  int half = threadIdx.x >> 5, lane = threadIdx.x & 31;
  int m = blockIdx.x * 8 + half;
  if (m >= M) return;
  int s = starts[m], e = starts[m + 1];
  float4 acc = {0.f, 0.f, 0.f, 0.f};
  for (int j = s; j < e; j++) {
    int vv = vlist[j];
    float4 val = ((const float4*)(B + (size_t)vv * 128))[lane];
    acc.x += val.x; acc.y += val.y; acc.z += val.z; acc.w += val.w;
  }
  int d = e - s;
  float inv = d > 0 ? 1.f / (float)d : 0.f;
  float4 o = {acc.x * inv, acc.y * inv, acc.z * inv, acc.w * inv};
  ((float4*)(Xe + (size_t)m * 128))[lane] = o;
  float ss = o.x + o.y + o.z + o.w;
  float qq = o.x * o.x + o.y * o.y + o.z * o.z + o.w * o.w;
  for (int mm = 1; mm < 32; mm <<= 1) {
    ss += __shfl_xor(ss, mm, 32);
    qq += __shfl_xor(qq, mm, 32);
  }
  if (lane == 0) { se[m] = ss; qe[m] = qq; }
}

// ============================ node gather (half-wave per node) ============================
// P[v] = suma * X[v];  Qb[v] = sum_p rstd_p * Xe[e_p];  invdeg, t2 = sumb/deg.
__global__ __launch_bounds__(256) void k_nodeg(
    const float* __restrict__ X, const float* __restrict__ Xe,
    const int* __restrict__ starts_v, const int* __restrict__ e_by_v,
    const float* __restrict__ sn, const float* __restrict__ qn,
    const float* __restrict__ se, const float* __restrict__ qe,
    float* __restrict__ P, float* __restrict__ Qb,
    float* __restrict__ invdeg, float* __restrict__ t2arr, int N) {
  int half = threadIdx.x >> 5, lane = threadIdx.x & 31;
  int v = blockIdx.x * 8 + half;
  if (v >= N) return;
  int s = starts_v[v], e = starts_v[v + 1];
  float svn = sn[v], qvn = qn[v];
  float4 acc = {0.f, 0.f, 0.f, 0.f};
  float suma = 0.f, sumb = 0.f;
  for (int j = s; j < e; j++) {
    int ee = e_by_v[j];
    float mu = (svn + se[ee]) * (1.f / 256.f);
    float e2 = (qvn + qe[ee]) * (1.f / 256.f);
    float rstd = rsqrtf(e2 - mu * mu + LNEPS);
    suma += rstd;
    sumb += mu * rstd;
    float4 vv = ((const float4*)(Xe + (size_t)ee * 128))[lane];
    acc.x += rstd * vv.x; acc.y += rstd * vv.y;
    acc.z += rstd * vv.z; acc.w += rstd * vv.w;
  }
  float4 xr = ((const float4*)(X + (size_t)v * 128))[lane];
  float4 pp = {suma * xr.x, suma * xr.y, suma * xr.z, suma * xr.w};
  ((float4*)(P + (size_t)v * 128))[lane] = pp;
  ((float4*)(Qb + (size_t)v * 128))[lane] = acc;
  if (lane == 0) {
    int d = e - s;
    float inv = d > 0 ? 1.f / (float)d : 0.f;
    invdeg[v] = inv;
    t2arr[v] = sumb * inv;
  }
}

// ============================ K=256 GEMM [P|Q] @ W2g + epilogue(blend+LN) ============================
__global__ __launch_bounds__(256) void k_tile256(
    const float* __restrict__ P, const float* __restrict__ Q,
    const float* __restrict__ W, const float* __restrict__ invdeg,
    const float* __restrict__ t2arr, const float* __restrict__ s_g,
    const float* __restrict__ c0, const float* __restrict__ X0,
    const float* __restrict__ wg, const float* __restrict__ wbn,
    float* __restrict__ out, int N) {
  __shared__ float Ash[32][260];
  __shared__ float Wsh[64][68];
  const int t = threadIdx.x;
  const int r0 = blockIdx.x * 32;
  for (int s = t; s < 2048; s += 256) {
    int r = s >> 6, c4 = (s & 63) * 4;
    float4 val = {0, 0, 0, 0};
    if (r0 + r < N) {
      val = (c4 < 128) ? *(const float4*)(P + (size_t)(r0 + r) * 128 + c4)
                       : *(const float4*)(Q + (size_t)(r0 + r) * 128 + (c4 - 128));
    }
    *(float4*)&Ash[r][c4] = val;
  }
  const int tc = t & 15, tr = t >> 4;
  float4 acc[2][2] = {{{0,0,0,0},{0,0,0,0}},{{0,0,0,0},{0,0,0,0}}};
  for (int ch = 0; ch < 2; ch++) {
    for (int kc = 0; kc < 4; kc++) {
      __syncthreads();
      for (int s = t; s < 1024; s += 256) {
        int k = s >> 4, c4 = (s & 15) * 4;
        *(float4*)&Wsh[k][c4] = *(const float4*)(W + (size_t)(kc * 64 + k) * 128 + ch * 64 + c4);
      }
      __syncthreads();
#pragma unroll 4
      for (int k = 0; k < 64; k += 4) {
        float4 w0 = *(const float4*)&Wsh[k + 0][tc * 4];
        float4 w1 = *(const float4*)&Wsh[k + 1][tc * 4];
        float4 w2 = *(const float4*)&Wsh[k + 2][tc * 4];
        float4 w3 = *(const float4*)&Wsh[k + 3][tc * 4];
        float4 a0 = *(const float4*)&Ash[tr * 2 + 0][kc * 64 + k];
        float4 a1 = *(const float4*)&Ash[tr * 2 + 1][kc * 64 + k];
        fma4(acc[ch][0], a0.x, w0); fma4(acc[ch][0], a0.y, w1);
        fma4(acc[ch][0], a0.z, w2); fma4(acc[ch][0], a0.w, w3);
        fma4(acc[ch][1], a1.x, w0); fma4(acc[ch][1], a1.y, w1);
        fma4(acc[ch][1], a1.z, w2); fma4(acc[ch][1], a1.w, w3);
      }
    }
  }
  __syncthreads();  // all Ash reads done
  // epilogue: Xv = gemm*invdeg - t2*s_g + flag*c0 ; blend with X0 -> Ash cols 0..127
  for (int r = 0; r < 2; r++) {
    int row = r0 + tr * 2 + r;
    if (row < N) {
      float t1 = invdeg[row], t2 = t2arr[row];
      float flag = t1 > 0.f ? 1.f : 0.f;
      for (int ch = 0; ch < 2; ch++) {
        int c = ch * 64 + tc * 4;
        float4 g = acc[ch][r];
        float4 sg = *(const float4*)(s_g + c);
        float4 cc = *(const float4*)(c0 + c);
        float4 x0 = *(const float4*)(X0 + (size_t)row * 128 + c);
        float4 z;
        z.x = 0.5f * (g.x * t1 - t2 * sg.x + flag * cc.x) + 0.5f * x0.x;
        z.y = 0.5f * (g.y * t1 - t2 * sg.y + flag * cc.y) + 0.5f * x0.y;
        z.z = 0.5f * (g.z * t1 - t2 * sg.z + flag * cc.z) + 0.5f * x0.z;
        z.w = 0.5f * (g.w * t1 - t2 * sg.w + flag * cc.w) + 0.5f * x0.w;
        *(float4*)&Ash[tr * 2 + r][c] = z;
      }
    }
  }
  __syncthreads();
  // LN rows (4 waves x 8 rows) with wg,wbn -> out
  int wv = t >> 6, lane = t & 63;
  for (int j = 0; j < 8; j++) {
    int r = wv * 8 + j;
    if (r0 + r < N) {
      float2 x = *(float2*)&Ash[r][lane * 2];
      float s = x.x + x.y, sq = x.x * x.x + x.y * x.y;
      for (int m = 1; m < 64; m <<= 1) { s += __shfl_xor(s, m); sq += __shfl_xor(sq, m); }
      float mu = s * (1.f / 128.f);
      float var = sq * (1.f / 128.f) - mu * mu;
      float rstd = rsqrtf(var + LNEPS);
      float2 gg = ((const float2*)wg)[lane];
      float2 bb = ((const float2*)wbn)[lane];
      float2 o;
      o.x = (x.x - mu) * rstd * gg.x + bb.x;
      o.y = (x.y - mu) * rstd * gg.y + bb.y;
      *(float2*)(out + (size_t)(r0 + r) * 128 + lane * 2) = o;
    }
  }
}

// ============================ classifier ============================
__global__ __launch_bounds__(128) void k_cls(
    const float* __restrict__ X, const float* __restrict__ W1,
    const float* __restrict__ b1, const float* __restrict__ lg,
    const float* __restrict__ lb, const float* __restrict__ W2,
    const float* __restrict__ b2, float* __restrict__ out, int N) {
  __shared__ float xr[128];
  int n = blockIdx.x, t = threadIdx.x;
  xr[t] = X[(size_t)n * 128 + t];
  __syncthreads();
  if (t < 64) {
    float a = b1[t];
    for (int k = 0; k < 128; k++) a += xr[k] * W1[k * 64 + t];
    float h = fmaxf(a, 0.f);
    float s = h, sq = h * h;
    for (int m = 1; m < 64; m <<= 1) { s += __shfl_xor(s, m); sq += __shfl_xor(sq, m); }
    float mu = s * (1.f / 64.f);
    float var = sq * (1.f / 64.f) - mu * mu;
    float rstd = rsqrtf(var + LNEPS);
    float hn = (h - mu) * rstd * lg[t] + lb[t];
    float c = hn * W2[t];
    for (int m = 1; m < 64; m <<= 1) c += __shfl_xor(c, m);
    if (t == 0) out[n] = c + b2[0];
  }
}

// ============================ driver ============================
static void run_branch(const float* x_in, const int* v, const int* e,
                       const float* lin_w, const float* lin_b,
                       const float* w1g, const float* w1bn, const float* w1w, const float* w1b,
                       const float* W2g, const float* s_g, const float* c0,
                       const float* wg, const float* wbn, const float* ww, const float* wb,
                       const float* cw1, const float* cb1, const float* cg, const float* cbn,
                       const float* cw2, const float* cb2,
                       float* X, float* X0, float* B, float* Qb, float* Xe,
                       float* sn, float* qn, float* se, float* qe,
                       float* invdeg, float* t2arr,
                       int* starts_e, int* starts_v, int* cursor, int* bsums,
                       int* v_by_e, int* e_by_v,
                       float* out, hipStream_t stream) {
  const int GN = (NN + 31) / 32;
  // CSR by hedge
  hipMemsetAsync(starts_e, 0, (NH + 1) * sizeof(int), stream);
  k_hist<<<(NI + 255) / 256, 256, 0, stream>>>(e, NI, starts_e);
  k_scan1<<<(NH + 1023) / 1024, 1024, 0, stream>>>(starts_e, NH, bsums);
  k_scan2<<<1, 1024, 0, stream>>>(bsums, (NH + 1023) / 1024);
  k_scan3<<<(NH + 255) / 256, 256, 0, stream>>>(starts_e, bsums, NH, NI);
  hipMemsetAsync(cursor, 0, NH * sizeof(int), stream);
  k_fill<<<(NI + 255) / 256, 256, 0, stream>>>(e, v, NI, starts_e, cursor, v_by_e);
  k_sort_seg<<<(NH + 255) / 256, 256, 0, stream>>>(starts_e, NH, v_by_e);
  // CSR by node
  hipMemsetAsync(starts_v, 0, (NN + 1) * sizeof(int), stream);
  k_hist<<<(NI + 255) / 256, 256, 0, stream>>>(v, NI, starts_v);
  k_scan1<<<(NN + 1023) / 1024, 1024, 0, stream>>>(starts_v, NN, bsums);
  k_scan2<<<1, 1024, 0, stream>>>(bsums, (NN + 1023) / 1024);
  k_scan3<<<(NN + 255) / 256, 256, 0, stream>>>(starts_v, bsums, NN, NI);
  hipMemsetAsync(cursor, 0, NN * sizeof(int), stream);
  k_fill<<<(NI + 255) / 256, 256, 0, stream>>>(v, e, NI, starts_v, cursor, e_by_v);
  k_sort_seg<<<(NN + 255) / 256, 256, 0, stream>>>(starts_v, NN, e_by_v);
  // input projection (+relu), duplicated into X and X0
  k_proj<<<GN, 256, 0, stream>>>(x_in, lin_w, lin_b, X, X0, NN);
  float* cur = X;  // layer input
  float* oth = B;  // scratch / W1 output / P / layer output
  for (int layer = 0; layer < 2; ++layer) {
    // oth = LN(cur)@W1 + b1 ; raw stats of cur -> sn,qn
    k_tile128<true, true, false><<<GN, 256, 0, stream>>>(
        cur, w1w, w1b, w1g, w1bn, sn, qn, oth, NN);
    // Xe = mean over hedge members of oth rows ; stats -> se,qe
    k_xe<<<(NH + 7) / 8, 256, 0, stream>>>(oth, starts_e, v_by_e, Xe, se, qe, NH);
    // P (into oth, dead) / Qb / invdeg / t2  (reads cur + Xe)
    k_nodeg<<<(NN + 7) / 8, 256, 0, stream>>>(cur, Xe, starts_v, e_by_v, sn, qn,
                                              se, qe, oth, Qb, invdeg, t2arr, NN);
    // cur = LN( 0.5*Xv + 0.5*X0 )   where Xv = ([P|Q]@W2g)*invdeg - t2*s_g + c0
    k_tile256<<<GN, 256, 0, stream>>>(oth, Qb, W2g, invdeg, t2arr, s_g, c0, X0,
                                      wg, wbn, cur, NN);
    // oth = relu(cur @ Ww + wb)  -> layer output
    k_tile128<false, true, true><<<GN, 256, 0, stream>>>(
        cur, ww, wb, nullptr, nullptr, nullptr, nullptr, oth, NN);
    float* tmp = cur; cur = oth; oth = tmp;
  }
  k_cls<<<NN, 128, 0, stream>>>(cur, cw1, cb1, cg, cbn, cw2, cb2, out, NN);
}

extern "C" void kernel_launch(void* const* d_in, const int* in_sizes, int n_in,
                              void* d_out, int out_size, void* d_ws, size_t ws_size,
                              hipStream_t stream) {
  (void)in_sizes; (void)n_in; (void)out_size; (void)ws_size;
  const float* x1 = (const float*)d_in[0];
  const int* v1 = (const int*)d_in[1];
  const int* e1 = (const int*)d_in[2];
  const float* x2 = (const float*)d_in[3];
  const int* v2 = (const int*)d_in[4];
  const int* e2 = (const int*)d_in[5];
  const float* lin_w = (const float*)d_in[6];
  const float* lin_b = (const float*)d_in[7];
  const float* w1g = (const float*)d_in[8];
  const float* w1bn = (const float*)d_in[9];
  const float* w1w = (const float*)d_in[10];
  const float* w1b = (const float*)d_in[11];
  const float* w2g = (const float*)d_in[12];
  const float* w2bn = (const float*)d_in[13];
  const float* w2w = (const float*)d_in[14];
  const float* w2b = (const float*)d_in[15];
  const float* wg = (const float*)d_in[16];
  const float* wbn = (const float*)d_in[17];
  const float* ww = (const float*)d_in[18];
  const float* wb = (const float*)d_in[19];
  const float* cw1 = (const float*)d_in[20];
  const float* cb1 = (const float*)d_in[21];
  const float* cg = (const float*)d_in[22];
  const float* cbn = (const float*)d_in[23];
  const float* cw2 = (const float*)d_in[24];
  const float* cb2 = (const float*)d_in[25];

  char* p = (char*)d_ws;
  auto alloc = [&](size_t bytes) {
    char* r = p;
    p += (bytes + 255) & ~(size_t)255;
    return r;
  };
  float* X = (float*)alloc((size_t)NN * 128 * 4);
  float* X0 = (float*)alloc((size_t)NN * 128 * 4);
  float* B = (float*)alloc((size_t)NN * 128 * 4);
  float* Qb = (float*)alloc((size_t)NN * 128 * 4);
  float* Xe = (float*)alloc((size_t)NH * 128 * 4);
  float* sn = (float*)alloc((size_t)NN * 4);
  float* qn = (float*)alloc((size_t)NN * 4);
  float* se = (float*)alloc((size_t)NH * 4);
  float* qe = (float*)alloc((size_t)NH * 4);
  float* invdeg = (float*)alloc((size_t)NN * 4);
  float* t2arr = (float*)alloc((size_t)NN * 4);
  int* starts_e = (int*)alloc((NH + 1) * 4);
  int* starts_v = (int*)alloc((NN + 1) * 4);
  int* cursor = (int*)alloc(NH * 4);
  int* bsums = (int*)alloc(1024 * 4);
  int* v_by_e = (int*)alloc((size_t)NI * 4);
  int* e_by_v = (int*)alloc((size_t)NI * 4);
  float* W2g = (float*)alloc((size_t)256 * 128 * 4);
  float* s_g = (float*)alloc(128 * 4);
  float* c0 = (float*)alloc(128 * 4);

  // one-time per launch: W2 precomputation (shared by both branches)
  k_prep_w2g<<<128, 256, 0, stream>>>(w2w, w2g, W2g);
  k_prep_sgc0<<<1, 128, 0, stream>>>(w2w, w2g, w2bn, w2b, s_g, c0);

  float* out = (float*)d_out;
  run_branch(x1, v1, e1, lin_w, lin_b, w1g, w1bn, w1w, w1b, W2g, s_g, c0,
             wg, wbn, ww, wb, cw1, cb1, cg, cbn, cw2, cb2,
             X, X0, B, Qb, Xe, sn, qn, se, qe, invdeg, t2arr,
             starts_e, starts_v, cursor, bsums, v_by_e, e_by_v, out, stream);
  run_branch(x2, v2, e2, lin_w, lin_b, w1g, w1bn, w1w, w1b, W2g, s_g, c0,
             wg, wbn, ww, wb, cw1, cb1, cg, cbn, cw2, cb2,
             X, X0, B, Qb, Xe, sn, qn, se, qe, invdeg, t2arr,
             starts_e, starts_v, cursor, bsums, v_by_e, e_by_v, out + NN, stream);
}

// Round 8
// 1843.142 us; speedup vs baseline: 1.5581x; 1.0971x over previous
//
#include <hip/hip_runtime.h>

#define NN 50000
#define NH 100000
#define NI 600000
#define FIN 512
#define HID 128
#define LNEPS 1e-5f

static __device__ __forceinline__ void fma4(float4& a, float s, const float4& w) {
  a.x += s * w.x; a.y += s * w.y; a.z += s * w.z; a.w += s * w.w;
}

// ============================ CSR build ============================
__global__ void k_hist(const int* __restrict__ idx, int n, int* __restrict__ deg) {
  int i = blockIdx.x * 256 + threadIdx.x;
  if (i < n) atomicAdd(&deg[idx[i]], 1);
}

__global__ __launch_bounds__(1024) void k_scan1(int* __restrict__ data, int m,
                                                int* __restrict__ bsums) {
  __shared__ int sh[1024];
  int tid = threadIdx.x;
  int i = blockIdx.x * 1024 + tid;
  int v = (i < m) ? data[i] : 0;
  sh[tid] = v;
  __syncthreads();
  for (int off = 1; off < 1024; off <<= 1) {
    int tv = (tid >= off) ? sh[tid - off] : 0;
    __syncthreads();
    sh[tid] += tv;
    __syncthreads();
  }
  if (i < m) data[i] = sh[tid] - v;  // exclusive
  if (tid == 1023) bsums[blockIdx.x] = sh[1023];
}

__global__ __launch_bounds__(1024) void k_scan2(int* __restrict__ bsums, int nb) {
  __shared__ int sh[1024];
  int tid = threadIdx.x;
  int v = (tid < nb) ? bsums[tid] : 0;
  sh[tid] = v;
  __syncthreads();
  for (int off = 1; off < 1024; off <<= 1) {
    int tv = (tid >= off) ? sh[tid - off] : 0;
    __syncthreads();
    sh[tid] += tv;
    __syncthreads();
  }
  if (tid < nb) bsums[tid] = sh[tid] - v;
}

__global__ void k_scan3(int* __restrict__ data, const int* __restrict__ bsums,
                        int m, int total) {
  int i = blockIdx.x * 256 + threadIdx.x;
  if (i < m) data[i] += bsums[i >> 10];
  if (i == 0) data[m] = total;
}

__global__ void k_fill(const int* __restrict__ key, const int* __restrict__ oth, int n,
                       const int* __restrict__ starts, int* __restrict__ cursor,
                       int* __restrict__ out_oth) {
  int i = blockIdx.x * 256 + threadIdx.x;
  if (i >= n) return;
  int k = key[i];
  int pos = starts[k] + atomicAdd(&cursor[k], 1);
  out_oth[pos] = oth[i];
}

// Sort each CSR segment ascending -> deterministic order every replay.
__global__ void k_sort_seg(const int* __restrict__ starts, int nseg,
                           int* __restrict__ vals) {
  int seg = blockIdx.x * 256 + threadIdx.x;
  if (seg >= nseg) return;
  int s = starts[seg], e = starts[seg + 1];
  int d = e - s;
  if (d <= 1) return;
  if (d <= 48) {
    int buf[48];
    for (int i = 0; i < d; i++) buf[i] = vals[s + i];
    for (int i = 1; i < d; i++) {
      int key = buf[i], j = i - 1;
      while (j >= 0 && buf[j] > key) { buf[j + 1] = buf[j]; j--; }
      buf[j + 1] = key;
    }
    for (int i = 0; i < d; i++) vals[s + i] = buf[i];
  } else {
    for (int i = s + 1; i < e; i++) {
      int key = vals[i], j = i - 1;
      while (j >= s && vals[j] > key) { vals[j + 1] = vals[j]; j--; }
      vals[j + 1] = key;
    }
  }
}

// ============================ W2 precompute ============================
__global__ void k_prep_w2g(const float* __restrict__ W2, const float* __restrict__ g2,
                           float* __restrict__ W2g) {
  int i = blockIdx.x * 256 + threadIdx.x;
  if (i >= 256 * 128) return;
  int k = i >> 7;
  W2g[i] = g2[k] * W2[i];
}

__global__ __launch_bounds__(128) void k_prep_sgc0(
    const float* __restrict__ W2, const float* __restrict__ g2,
    const float* __restrict__ b2, const float* __restrict__ bias2,
    float* __restrict__ s_g, float* __restrict__ c0) {
  int t = threadIdx.x;
  float sg = 0.f, cc = 0.f;
  for (int k = 0; k < 256; k++) {
    float w = W2[k * 128 + t];
    sg += g2[k] * w;
    cc += b2[k] * w;
  }
  s_g[t] = sg;
  c0[t] = cc + bias2[t];
}

// ============================ GEMM primitives ============================
// Ash: 32x128 A tile (stride 132). Wsh: 32x64 W chunk (stride 68).
// Thread (tc=t&15, tr=t>>4): rows tr*2..+1, cols tc*4..+3 within a 64-col half.
static __device__ __forceinline__ void stage_w(float (*Wsh)[68], const float* __restrict__ W,
                                               int ldw, int row0, int col0, int t) {
  for (int s = t; s < 512; s += 256) {
    int k = s >> 4, c4 = (s & 15) * 4;
    *(float4*)&Wsh[k][c4] = *(const float4*)(W + (size_t)(row0 + k) * ldw + col0 + c4);
  }
}

static __device__ __forceinline__ void inner32(const float (*Ash)[132], const float (*Wsh)[68],
                                               int kb, int tc, int tr,
                                               float4& acc0, float4& acc1) {
#pragma unroll
  for (int k = 0; k < 32; k += 4) {
    float4 w0 = *(const float4*)&Wsh[k + 0][tc * 4];
    float4 w1 = *(const float4*)&Wsh[k + 1][tc * 4];
    float4 w2 = *(const float4*)&Wsh[k + 2][tc * 4];
    float4 w3 = *(const float4*)&Wsh[k + 3][tc * 4];
    float4 a0 = *(const float4*)&Ash[tr * 2 + 0][kb + k];
    float4 a1 = *(const float4*)&Ash[tr * 2 + 1][kb + k];
    fma4(acc0, a0.x, w0); fma4(acc0, a0.y, w1); fma4(acc0, a0.z, w2); fma4(acc0, a0.w, w3);
    fma4(acc1, a1.x, w0); fma4(acc1, a1.y, w1); fma4(acc1, a1.z, w2); fma4(acc1, a1.w, w3);
  }
}

static __device__ __forceinline__ void load_a128(float (*Ash)[132], const float* __restrict__ A,
                                                 int r0, int N, int t) {
  for (int s = t; s < 1024; s += 256) {
    int r = s >> 5, c4 = (s & 31) * 4;
    float4 val = {0, 0, 0, 0};
    if (r0 + r < N) val = *(const float4*)(A + (size_t)(r0 + r) * 128 + c4);
    *(float4*)&Ash[r][c4] = val;
  }
}

// LN rows of Ash in place (stats optional), 4 waves x 8 rows.
template <bool STATS>
static __device__ __forceinline__ void ln_tile(float (*Ash)[132], const float* __restrict__ g,
                                               const float* __restrict__ b,
                                               float* __restrict__ sn, float* __restrict__ qn,
                                               int r0, int N, int t) {
  int wv = t >> 6, lane = t & 63;
  for (int j = 0; j < 8; j++) {
    int r = wv * 8 + j;
    if (r0 + r < N) {
      float2 x = *(float2*)&Ash[r][lane * 2];
      float s = x.x + x.y, sq = x.x * x.x + x.y * x.y;
      for (int m = 1; m < 64; m <<= 1) { s += __shfl_xor(s, m); sq += __shfl_xor(sq, m); }
      if (STATS && lane == 0) { sn[r0 + r] = s; qn[r0 + r] = sq; }
      float mu = s * (1.f / 128.f);
      float var = sq * (1.f / 128.f) - mu * mu;
      float rstd = rsqrtf(var + LNEPS);
      float2 gg = ((const float2*)g)[lane];
      float2 bb = ((const float2*)b)[lane];
      float2 o;
      o.x = (x.x - mu) * rstd * gg.x + bb.x;
      o.y = (x.y - mu) * rstd * gg.y + bb.y;
      *(float2*)&Ash[r][lane * 2] = o;
    }
  }
}

// ============================ proj + relu + LN-stats + W1 GEMM ============================
__global__ __launch_bounds__(256) void k_proj_fused(
    const float* __restrict__ x_in, const float* __restrict__ lin_w,
    const float* __restrict__ lin_b, const float* __restrict__ w1g,
    const float* __restrict__ w1bn, const float* __restrict__ w1w,
    const float* __restrict__ w1b, float* __restrict__ X, float* __restrict__ X0,
    float* __restrict__ B, float* __restrict__ sn, float* __restrict__ qn, int N) {
  __shared__ float Ash[32][132];
  __shared__ float Wsh[32][68];
  const int t = threadIdx.x;
  const int r0 = blockIdx.x * 32;
  const int tc = t & 15, tr = t >> 4;
  float4 acc0[2] = {{0,0,0,0},{0,0,0,0}}, acc1[2] = {{0,0,0,0},{0,0,0,0}};
  for (int kq = 0; kq < 4; kq++) {
    __syncthreads();
    for (int s = t; s < 1024; s += 256) {
      int r = s >> 5, c4 = (s & 31) * 4;
      float4 val = {0, 0, 0, 0};
      if (r0 + r < N) val = *(const float4*)(x_in + (size_t)(r0 + r) * 512 + kq * 128 + c4);
      *(float4*)&Ash[r][c4] = val;
    }
    for (int ch = 0; ch < 2; ch++)
      for (int kc = 0; kc < 4; kc++) {
        __syncthreads();
        stage_w(Wsh, lin_w, 128, kq * 128 + kc * 32, ch * 64, t);
        __syncthreads();
        inner32((const float(*)[132])Ash, (const float(*)[68])Wsh, kc * 32, tc, tr,
                acc0[ch], acc1[ch]);
      }
  }
  __syncthreads();
  // relu + write X, X0, and stash Z into Ash
  for (int ch = 0; ch < 2; ch++) {
    int c = ch * 64 + tc * 4;
    float4 bb = *(const float4*)(lin_b + c);
    int row0 = r0 + tr * 2;
    float4 z0, z1;
    z0.x = fmaxf(acc0[ch].x + bb.x, 0.f); z0.y = fmaxf(acc0[ch].y + bb.y, 0.f);
    z0.z = fmaxf(acc0[ch].z + bb.z, 0.f); z0.w = fmaxf(acc0[ch].w + bb.w, 0.f);
    z1.x = fmaxf(acc1[ch].x + bb.x, 0.f); z1.y = fmaxf(acc1[ch].y + bb.y, 0.f);
    z1.z = fmaxf(acc1[ch].z + bb.z, 0.f); z1.w = fmaxf(acc1[ch].w + bb.w, 0.f);
    if (row0 < N) {
      *(float4*)(X + (size_t)row0 * 128 + c) = z0;
      *(float4*)(X0 + (size_t)row0 * 128 + c) = z0;
      *(float4*)&Ash[tr * 2][c] = z0;
    }
    if (row0 + 1 < N) {
      *(float4*)(X + (size_t)(row0 + 1) * 128 + c) = z1;
      *(float4*)(X0 + (size_t)(row0 + 1) * 128 + c) = z1;
      *(float4*)&Ash[tr * 2 + 1][c] = z1;
    }
  }
  __syncthreads();
  ln_tile<true>(Ash, w1g, w1bn, sn, qn, r0, N, t);
  // B = LN(Z) @ w1w + w1b
  float4 f0[2] = {{0,0,0,0},{0,0,0,0}}, f1[2] = {{0,0,0,0},{0,0,0,0}};
  for (int ch = 0; ch < 2; ch++)
    for (int kc = 0; kc < 4; kc++) {
      __syncthreads();
      stage_w(Wsh, w1w, 128, kc * 32, ch * 64, t);
      __syncthreads();
      inner32((const float(*)[132])Ash, (const float(*)[68])Wsh, kc * 32, tc, tr,
              f0[ch], f1[ch]);
    }
  for (int ch = 0; ch < 2; ch++) {
    int c = ch * 64 + tc * 4;
    float4 bb = *(const float4*)(w1b + c);
    int row0 = r0 + tr * 2;
    if (row0 < N) {
      float4 o = {f0[ch].x + bb.x, f0[ch].y + bb.y, f0[ch].z + bb.z, f0[ch].w + bb.w};
      *(float4*)(B + (size_t)row0 * 128 + c) = o;
    }
    if (row0 + 1 < N) {
      float4 o = {f1[ch].x + bb.x, f1[ch].y + bb.y, f1[ch].z + bb.z, f1[ch].w + bb.w};
      *(float4*)(B + (size_t)(row0 + 1) * 128 + c) = o;
    }
  }
}

// ============================ hedge mean gather (half-wave per hedge) ============================
__global__ __launch_bounds__(256) void k_xe(
    const float* __restrict__ B, const int* __restrict__ starts,
    const int* __restrict__ vlist, float* __restrict__ Xe,
    float* __restrict__ se, float* __restrict__ qe, int M) {
  int half = threadIdx.x >> 5, lane = threadIdx.x & 31;
  int m = blockIdx.x * 8 + half;
  if (m >= M) return;
  int s = starts[m], e = starts[m + 1];
  float4 acc = {0.f, 0.f, 0.f, 0.f};
  for (int j = s; j < e; j++) {
    int vv = vlist[j];
    float4 val = ((const float4*)(B + (size_t)vv * 128))[lane];
    acc.x += val.x; acc.y += val.y; acc.z += val.z; acc.w += val.w;
  }
  int d = e - s;
  float inv = d > 0 ? 1.f / (float)d : 0.f;
  float4 o = {acc.x * inv, acc.y * inv, acc.z * inv, acc.w * inv};
  ((float4*)(Xe + (size_t)m * 128))[lane] = o;
  float ss = o.x + o.y + o.z + o.w;
  float qq = o.x * o.x + o.y * o.y + o.z * o.z + o.w * o.w;
  for (int mm = 1; mm < 32; mm <<= 1) {
    ss += __shfl_xor(ss, mm, 32);
    qq += __shfl_xor(qq, mm, 32);
  }
  if (lane == 0) { se[m] = ss; qe[m] = qq; }
}

// ============================ node gather (half-wave per node) ============================
__global__ __launch_bounds__(256) void k_nodeg(
    const float* __restrict__ X, const float* __restrict__ Xe,
    const int* __restrict__ starts_v, const int* __restrict__ e_by_v,
    const float* __restrict__ sn, const float* __restrict__ qn,
    const float* __restrict__ se, const float* __restrict__ qe,
    float* __restrict__ P, float* __restrict__ Qb,
    float* __restrict__ invdeg, float* __restrict__ t2arr, int N) {
  int half = threadIdx.x >> 5, lane = threadIdx.x & 31;
  int v = blockIdx.x * 8 + half;
  if (v >= N) return;
  int s = starts_v[v], e = starts_v[v + 1];
  float svn = sn[v], qvn = qn[v];
  float4 acc = {0.f, 0.f, 0.f, 0.f};
  float suma = 0.f, sumb = 0.f;
  for (int j = s; j < e; j++) {
    int ee = e_by_v[j];
    float mu = (svn + se[ee]) * (1.f / 256.f);
    float e2 = (qvn + qe[ee]) * (1.f / 256.f);
    float rstd = rsqrtf(e2 - mu * mu + LNEPS);
    suma += rstd;
    sumb += mu * rstd;
    float4 vv = ((const float4*)(Xe + (size_t)ee * 128))[lane];
    acc.x += rstd * vv.x; acc.y += rstd * vv.y;
    acc.z += rstd * vv.z; acc.w += rstd * vv.w;
  }
  float4 xr = ((const float4*)(X + (size_t)v * 128))[lane];
  float4 pp = {suma * xr.x, suma * xr.y, suma * xr.z, suma * xr.w};
  ((float4*)(P + (size_t)v * 128))[lane] = pp;
  ((float4*)(Qb + (size_t)v * 128))[lane] = acc;
  if (lane == 0) {
    int d = e - s;
    float inv = d > 0 ? 1.f / (float)d : 0.f;
    invdeg[v] = inv;
    t2arr[v] = sumb * inv;
  }
}

// ============================ [P|Q]@W2g + epilogue(blend+LN) ============================
__global__ __launch_bounds__(256) void k_conv2(
    const float* __restrict__ P, const float* __restrict__ Q,
    const float* __restrict__ W, const float* __restrict__ invdeg,
    const float* __restrict__ t2arr, const float* __restrict__ s_g,
    const float* __restrict__ c0, const float* __restrict__ X0,
    const float* __restrict__ wg, const float* __restrict__ wbn,
    float* __restrict__ out, int N) {
  __shared__ float Ash[32][132];
  __shared__ float Wsh[32][68];
  const int t = threadIdx.x;
  const int r0 = blockIdx.x * 32;
  const int tc = t & 15, tr = t >> 4;
  float4 acc0[2] = {{0,0,0,0},{0,0,0,0}}, acc1[2] = {{0,0,0,0},{0,0,0,0}};
  for (int ph = 0; ph < 2; ph++) {
    __syncthreads();
    load_a128(Ash, ph ? Q : P, r0, N, t);
    for (int ch = 0; ch < 2; ch++)
      for (int kc = 0; kc < 4; kc++) {
        __syncthreads();
        stage_w(Wsh, W, 128, ph * 128 + kc * 32, ch * 64, t);
        __syncthreads();
        inner32((const float(*)[132])Ash, (const float(*)[68])Wsh, kc * 32, tc, tr,
                acc0[ch], acc1[ch]);
      }
  }
  __syncthreads();
  // epilogue: Xv = G*invdeg - t2*s_g + flag*c0; blend with X0 -> Ash
  for (int r = 0; r < 2; r++) {
    int row = r0 + tr * 2 + r;
    if (row < N) {
      float t1 = invdeg[row], t2 = t2arr[row];
      float flag = t1 > 0.f ? 1.f : 0.f;
      for (int ch = 0; ch < 2; ch++) {
        int c = ch * 64 + tc * 4;
        float4 g = r ? acc1[ch] : acc0[ch];
        float4 sg = *(const float4*)(s_g + c);
        float4 cc = *(const float4*)(c0 + c);
        float4 x0 = *(const float4*)(X0 + (size_t)row * 128 + c);
        float4 z;
        z.x = 0.5f * (g.x * t1 - t2 * sg.x + flag * cc.x) + 0.5f * x0.x;
        z.y = 0.5f * (g.y * t1 - t2 * sg.y + flag * cc.y) + 0.5f * x0.y;
        z.z = 0.5f * (g.z * t1 - t2 * sg.z + flag * cc.z) + 0.5f * x0.z;
        z.w = 0.5f * (g.w * t1 - t2 * sg.w + flag * cc.w) + 0.5f * x0.w;
        *(float4*)&Ash[tr * 2 + r][c] = z;
      }
    }
  }
  __syncthreads();
  // LN -> out
  int wv = t >> 6, lane = t & 63;
  for (int j = 0; j < 8; j++) {
    int r = wv * 8 + j;
    if (r0 + r < N) {
      float2 x = *(float2*)&Ash[r][lane * 2];
      float s = x.x + x.y, sq = x.x * x.x + x.y * x.y;
      for (int m = 1; m < 64; m <<= 1) { s += __shfl_xor(s, m); sq += __shfl_xor(sq, m); }
      float mu = s * (1.f / 128.f);
      float var = sq * (1.f / 128.f) - mu * mu;
      float rstd = rsqrtf(var + LNEPS);
      float2 gg = ((const float2*)wg)[lane];
      float2 bb = ((const float2*)wbn)[lane];
      float2 o;
      o.x = (x.x - mu) * rstd * gg.x + bb.x;
      o.y = (x.y - mu) * rstd * gg.y + bb.y;
      *(float2*)(out + (size_t)(r0 + r) * 128 + lane * 2) = o;
    }
  }
}

// ============================ W-GEMM+relu -> X ; LN-stats ; W1 GEMM -> B ============================
__global__ __launch_bounds__(256) void k_wnext(
    const float* __restrict__ Xin, const float* __restrict__ Ww,
    const float* __restrict__ wb, const float* __restrict__ w1g,
    const float* __restrict__ w1bn, const float* __restrict__ w1w,
    const float* __restrict__ w1b, float* __restrict__ Xout,
    float* __restrict__ B, float* __restrict__ sn, float* __restrict__ qn, int N) {
  __shared__ float Ash[32][132];
  __shared__ float Wsh[32][68];
  const int t = threadIdx.x;
  const int r0 = blockIdx.x * 32;
  const int tc = t & 15, tr = t >> 4;
  load_a128(Ash, Xin, r0, N, t);
  float4 acc0[2] = {{0,0,0,0},{0,0,0,0}}, acc1[2] = {{0,0,0,0},{0,0,0,0}};
  for (int ch = 0; ch < 2; ch++)
    for (int kc = 0; kc < 4; kc++) {
      __syncthreads();
      stage_w(Wsh, Ww, 128, kc * 32, ch * 64, t);
      __syncthreads();
      inner32((const float(*)[132])Ash, (const float(*)[68])Wsh, kc * 32, tc, tr,
              acc0[ch], acc1[ch]);
    }
  __syncthreads();
  for (int ch = 0; ch < 2; ch++) {
    int c = ch * 64 + tc * 4;
    float4 bb = *(const float4*)(wb + c);
    int row0 = r0 + tr * 2;
    float4 z0, z1;
    z0.x = fmaxf(acc0[ch].x + bb.x, 0.f); z0.y = fmaxf(acc0[ch].y + bb.y, 0.f);
    z0.z = fmaxf(acc0[ch].z + bb.z, 0.f); z0.w = fmaxf(acc0[ch].w + bb.w, 0.f);
    z1.x = fmaxf(acc1[ch].x + bb.x, 0.f); z1.y = fmaxf(acc1[ch].y + bb.y, 0.f);
    z1.z = fmaxf(acc1[ch].z + bb.z, 0.f); z1.w = fmaxf(acc1[ch].w + bb.w, 0.f);
    if (row0 < N) {
      *(float4*)(Xout + (size_t)row0 * 128 + c) = z0;
      *(float4*)&Ash[tr * 2][c] = z0;
    }
    if (row0 + 1 < N) {
      *(float4*)(Xout + (size_t)(row0 + 1) * 128 + c) = z1;
      *(float4*)&Ash[tr * 2 + 1][c] = z1;
    }
  }
  __syncthreads();
  ln_tile<true>(Ash, w1g, w1bn, sn, qn, r0, N, t);
  float4 f0[2] = {{0,0,0,0},{0,0,0,0}}, f1[2] = {{0,0,0,0},{0,0,0,0}};
  for (int ch = 0; ch < 2; ch++)
    for (int kc = 0; kc < 4; kc++) {
      __syncthreads();
      stage_w(Wsh, w1w, 128, kc * 32, ch * 64, t);
      __syncthreads();
      inner32((const float(*)[132])Ash, (const float(*)[68])Wsh, kc * 32, tc, tr,
              f0[ch], f1[ch]);
    }
  for (int ch = 0; ch < 2; ch++) {
    int c = ch * 64 + tc * 4;
    float4 bb = *(const float4*)(w1b + c);
    int row0 = r0 + tr * 2;
    if (row0 < N) {
      float4 o = {f0[ch].x + bb.x, f0[ch].y + bb.y, f0[ch].z + bb.z, f0[ch].w + bb.w};
      *(float4*)(B + (size_t)row0 * 128 + c) = o;
    }
    if (row0 + 1 < N) {
      float4 o = {f1[ch].x + bb.x, f1[ch].y + bb.y, f1[ch].z + bb.z, f1[ch].w + bb.w};
      *(float4*)(B + (size_t)(row0 + 1) * 128 + c) = o;
    }
  }
}

// ============================ W-GEMM+relu ; classifier (cw1 GEMM, LN64, dot) ============================
__global__ __launch_bounds__(256) void k_wcls(
    const float* __restrict__ Xin, const float* __restrict__ Ww,
    const float* __restrict__ wb, const float* __restrict__ cw1,
    const float* __restrict__ cb1, const float* __restrict__ cg,
    const float* __restrict__ cbn, const float* __restrict__ cw2,
    const float* __restrict__ cb2, float* __restrict__ out, int N) {
  __shared__ float Ash[32][132];
  __shared__ float Wsh[32][68];
  const int t = threadIdx.x;
  const int r0 = blockIdx.x * 32;
  const int tc = t & 15, tr = t >> 4;
  load_a128(Ash, Xin, r0, N, t);
  float4 acc0[2] = {{0,0,0,0},{0,0,0,0}}, acc1[2] = {{0,0,0,0},{0,0,0,0}};
  for (int ch = 0; ch < 2; ch++)
    for (int kc = 0; kc < 4; kc++) {
      __syncthreads();
      stage_w(Wsh, Ww, 128, kc * 32, ch * 64, t);
      __syncthreads();
      inner32((const float(*)[132])Ash, (const float(*)[68])Wsh, kc * 32, tc, tr,
              acc0[ch], acc1[ch]);
    }
  __syncthreads();
  for (int ch = 0; ch < 2; ch++) {
    int c = ch * 64 + tc * 4;
    float4 bb = *(const float4*)(wb + c);
    int row0 = r0 + tr * 2;
    if (row0 < N) {
      float4 z;
      z.x = fmaxf(acc0[ch].x + bb.x, 0.f); z.y = fmaxf(acc0[ch].y + bb.y, 0.f);
      z.z = fmaxf(acc0[ch].z + bb.z, 0.f); z.w = fmaxf(acc0[ch].w + bb.w, 0.f);
      *(float4*)&Ash[tr * 2][c] = z;
    }
    if (row0 + 1 < N) {
      float4 z;
      z.x = fmaxf(acc1[ch].x + bb.x, 0.f); z.y = fmaxf(acc1[ch].y + bb.y, 0.f);
      z.z = fmaxf(acc1[ch].z + bb.z, 0.f); z.w = fmaxf(acc1[ch].w + bb.w, 0.f);
      *(float4*)&Ash[tr * 2 + 1][c] = z;
    }
  }
  // H = relu(Z @ cw1 + cb1): 64 cols
  float4 h0 = {0,0,0,0}, h1 = {0,0,0,0};
  for (int kc = 0; kc < 4; kc++) {
    __syncthreads();
    stage_w(Wsh, cw1, 64, kc * 32, 0, t);
    __syncthreads();
    inner32((const float(*)[132])Ash, (const float(*)[68])Wsh, kc * 32, tc, tr, h0, h1);
  }
  __syncthreads();
  {
    int c = tc * 4;
    float4 bb = *(const float4*)(cb1 + c);
    float4 z;
    z.x = fmaxf(h0.x + bb.x, 0.f); z.y = fmaxf(h0.y + bb.y, 0.f);
    z.z = fmaxf(h0.z + bb.z, 0.f); z.w = fmaxf(h0.w + bb.w, 0.f);
    *(float4*)&Wsh[tr * 2][c] = z;
    z.x = fmaxf(h1.x + bb.x, 0.f); z.y = fmaxf(h1.y + bb.y, 0.f);
    z.z = fmaxf(h1.z + bb.z, 0.f); z.w = fmaxf(h1.w + bb.w, 0.f);
    *(float4*)&Wsh[tr * 2 + 1][c] = z;
  }
  __syncthreads();
  // LN(64) + dot(cw2) per row; 4 waves x 8 rows, 64 lanes = 64 cols
  int wv = t >> 6, lane = t & 63;
  for (int j = 0; j < 8; j++) {
    int r = wv * 8 + j;
    if (r0 + r < N) {
      float h = Wsh[r][lane];
      float s = h, sq = h * h;
      for (int m = 1; m < 64; m <<= 1) { s += __shfl_xor(s, m); sq += __shfl_xor(sq, m); }
      float mu = s * (1.f / 64.f);
      float var = sq * (1.f / 64.f) - mu * mu;
      float rstd = rsqrtf(var + LNEPS);
      float hn = (h - mu) * rstd * cg[lane] + cbn[lane];
      float c = hn * cw2[lane];
      for (int m = 1; m < 64; m <<= 1) c += __shfl_xor(c, m);
      if (lane == 0) out[r0 + r] = c + cb2[0];
    }
  }
}

// ============================ driver ============================
static void run_branch(const float* x_in, const int* v, const int* e,
                       const float* lin_w, const float* lin_b,
                       const float* w1g, const float* w1bn, const float* w1w, const float* w1b,
                       const float* W2g, const float* s_g, const float* c0,
                       const float* wg, const float* wbn, const float* ww, const float* wb,
                       const float* cw1, const float* cb1, const float* cg, const float* cbn,
                       const float* cw2, const float* cb2,
                       float* X, float* X0, float* B, float* Qb, float* Xe,
                       float* sn, float* qn, float* se, float* qe,
                       float* invdeg, float* t2arr,
                       int* starts_e, int* starts_v, int* cursor, int* bsums,
                       int* v_by_e, int* e_by_v,
                       float* out, hipStream_t stream) {
  const int GN = (NN + 31) / 32;
  // CSR by hedge
  hipMemsetAsync(starts_e, 0, (NH + 1) * sizeof(int), stream);
  k_hist<<<(NI + 255) / 256, 256, 0, stream>>>(e, NI, starts_e);
  k_scan1<<<(NH + 1023) / 1024, 1024, 0, stream>>>(starts_e, NH, bsums);
  k_scan2<<<1, 1024, 0, stream>>>(bsums, (NH + 1023) / 1024);
  k_scan3<<<(NH + 255) / 256, 256, 0, stream>>>(starts_e, bsums, NH, NI);
  hipMemsetAsync(cursor, 0, NH * sizeof(int), stream);
  k_fill<<<(NI + 255) / 256, 256, 0, stream>>>(e, v, NI, starts_e, cursor, v_by_e);
  k_sort_seg<<<(NH + 255) / 256, 256, 0, stream>>>(starts_e, NH, v_by_e);
  // CSR by node
  hipMemsetAsync(starts_v, 0, (NN + 1) * sizeof(int), stream);
  k_hist<<<(NI + 255) / 256, 256, 0, stream>>>(v, NI, starts_v);
  k_scan1<<<(NN + 1023) / 1024, 1024, 0, stream>>>(starts_v, NN, bsums);
  k_scan2<<<1, 1024, 0, stream>>>(bsums, (NN + 1023) / 1024);
  k_scan3<<<(NN + 255) / 256, 256, 0, stream>>>(starts_v, bsums, NN, NI);
  hipMemsetAsync(cursor, 0, NN * sizeof(int), stream);
  k_fill<<<(NI + 255) / 256, 256, 0, stream>>>(v, e, NI, starts_v, cursor, e_by_v);
  k_sort_seg<<<(NN + 255) / 256, 256, 0, stream>>>(starts_v, NN, e_by_v);
  // proj + relu -> X,X0 ; LN-stats -> sn,qn ; W1 GEMM -> B
  k_proj_fused<<<GN, 256, 0, stream>>>(x_in, lin_w, lin_b, w1g, w1bn, w1w, w1b,
                                       X, X0, B, sn, qn, NN);
  for (int layer = 0; layer < 2; ++layer) {
    k_xe<<<NH / 8, 256, 0, stream>>>(B, starts_e, v_by_e, Xe, se, qe, NH);
    k_nodeg<<<(NN + 7) / 8, 256, 0, stream>>>(X, Xe, starts_v, e_by_v, sn, qn,
                                              se, qe, B, Qb, invdeg, t2arr, NN);
    k_conv2<<<GN, 256, 0, stream>>>(B, Qb, W2g, invdeg, t2arr, s_g, c0, X0,
                                    wg, wbn, X, NN);
    if (layer == 0) {
      k_wnext<<<GN, 256, 0, stream>>>(X, ww, wb, w1g, w1bn, w1w, w1b,
                                      X, B, sn, qn, NN);
    } else {
      k_wcls<<<GN, 256, 0, stream>>>(X, ww, wb, cw1, cb1, cg, cbn, cw2, cb2,
                                     out, NN);
    }
  }
}

extern "C" void kernel_launch(void* const* d_in, const int* in_sizes, int n_in,
                              void* d_out, int out_size, void* d_ws, size_t ws_size,
                              hipStream_t stream) {
  (void)in_sizes; (void)n_in; (void)out_size; (void)ws_size;
  const float* x1 = (const float*)d_in[0];
  const int* v1 = (const int*)d_in[1];
  const int* e1 = (const int*)d_in[2];
  const float* x2 = (const float*)d_in[3];
  const int* v2 = (const int*)d_in[4];
  const int* e2 = (const int*)d_in[5];
  const float* lin_w = (const float*)d_in[6];
  const float* lin_b = (const float*)d_in[7];
  const float* w1g = (const float*)d_in[8];
  const float* w1bn = (const float*)d_in[9];
  const float* w1w = (const float*)d_in[10];
  const float* w1b = (const float*)d_in[11];
  const float* w2g = (const float*)d_in[12];
  const float* w2bn = (const float*)d_in[13];
  const float* w2w = (const float*)d_in[14];
  const float* w2b = (const float*)d_in[15];
  const float* wg = (const float*)d_in[16];
  const float* wbn = (const float*)d_in[17];
  const float* ww = (const float*)d_in[18];
  const float* wb = (const float*)d_in[19];
  const float* cw1 = (const float*)d_in[20];
  const float* cb1 = (const float*)d_in[21];
  const float* cg = (const float*)d_in[22];
  const float* cbn = (const float*)d_in[23];
  const float* cw2 = (const float*)d_in[24];
  const float* cb2 = (const float*)d_in[25];

  char* p = (char*)d_ws;
  auto alloc = [&](size_t bytes) {
    char* r = p;
    p += (bytes + 255) & ~(size_t)255;
    return r;
  };
  float* X = (float*)alloc((size_t)NN * 128 * 4);
  float* X0 = (float*)alloc((size_t)NN * 128 * 4);
  float* B = (float*)alloc((size_t)NN * 128 * 4);
  float* Qb = (float*)alloc((size_t)NN * 128 * 4);
  float* Xe = (float*)alloc((size_t)NH * 128 * 4);
  float* sn = (float*)alloc((size_t)NN * 4);
  float* qn = (float*)alloc((size_t)NN * 4);
  float* se = (float*)alloc((size_t)NH * 4);
  float* qe = (float*)alloc((size_t)NH * 4);
  float* invdeg = (float*)alloc((size_t)NN * 4);
  float* t2arr = (float*)alloc((size_t)NN * 4);
  int* starts_e = (int*)alloc((NH + 1) * 4);
  int* starts_v = (int*)alloc((NN + 1) * 4);
  int* cursor = (int*)alloc(NH * 4);
  int* bsums = (int*)alloc(1024 * 4);
  int* v_by_e = (int*)alloc((size_t)NI * 4);
  int* e_by_v = (int*)alloc((size_t)NI * 4);
  float* W2g = (float*)alloc((size_t)256 * 128 * 4);
  float* s_g = (float*)alloc(128 * 4);
  float* c0 = (float*)alloc(128 * 4);

  // one-time per launch: W2 precomputation (shared by both branches)
  k_prep_w2g<<<128, 256, 0, stream>>>(w2w, w2g, W2g);
  k_prep_sgc0<<<1, 128, 0, stream>>>(w2w, w2g, w2bn, w2b, s_g, c0);

  float* out = (float*)d_out;
  run_branch(x1, v1, e1, lin_w, lin_b, w1g, w1bn, w1w, w1b, W2g, s_g, c0,
             wg, wbn, ww, wb, cw1, cb1, cg, cbn, cw2, cb2,
             X, X0, B, Qb, Xe, sn, qn, se, qe, invdeg, t2arr,
             starts_e, starts_v, cursor, bsums, v_by_e, e_by_v, out, stream);
  run_branch(x2, v2, e2, lin_w, lin_b, w1g, w1bn, w1w, w1b, W2g, s_g, c0,
             wg, wbn, ww, wb, cw1, cb1, cg, cbn, cw2, cb2,
             X, X0, B, Qb, Xe, sn, qn, se, qe, invdeg, t2arr,
             starts_e, starts_v, cursor, bsums, v_by_e, e_by_v, out + NN, stream);
}

// Round 10
// 1839.806 us; speedup vs baseline: 1.5609x; 1.0018x over previous
//
#include <hip/hip_runtime.h>

#define NN 50000
#define NH 100000
#define NI 600000
#define FIN 512
#define HID 128
#define LNEPS 1e-5f

static __device__ __forceinline__ void fma4(float4& a, float s, const float4& w) {
  a.x += s * w.x; a.y += s * w.y; a.z += s * w.z; a.w += s * w.w;
}

// ============================ CSR build ============================
__global__ void k_hist(const int* __restrict__ idx, int n, int* __restrict__ deg) {
  int i = blockIdx.x * 256 + threadIdx.x;
  if (i < n) atomicAdd(&deg[idx[i]], 1);
}

__global__ __launch_bounds__(1024) void k_scan1(int* __restrict__ data, int m,
                                                int* __restrict__ bsums) {
  __shared__ int sh[1024];
  int tid = threadIdx.x;
  int i = blockIdx.x * 1024 + tid;
  int v = (i < m) ? data[i] : 0;
  sh[tid] = v;
  __syncthreads();
  for (int off = 1; off < 1024; off <<= 1) {
    int tv = (tid >= off) ? sh[tid - off] : 0;
    __syncthreads();
    sh[tid] += tv;
    __syncthreads();
  }
  if (i < m) data[i] = sh[tid] - v;  // exclusive
  if (tid == 1023) bsums[blockIdx.x] = sh[1023];
}

__global__ __launch_bounds__(1024) void k_scan2(int* __restrict__ bsums, int nb) {
  __shared__ int sh[1024];
  int tid = threadIdx.x;
  int v = (tid < nb) ? bsums[tid] : 0;
  sh[tid] = v;
  __syncthreads();
  for (int off = 1; off < 1024; off <<= 1) {
    int tv = (tid >= off) ? sh[tid - off] : 0;
    __syncthreads();
    sh[tid] += tv;
    __syncthreads();
  }
  if (tid < nb) bsums[tid] = sh[tid] - v;
}

__global__ void k_scan3(int* __restrict__ data, const int* __restrict__ bsums,
                        int m, int total) {
  int i = blockIdx.x * 256 + threadIdx.x;
  if (i < m) data[i] += bsums[i >> 10];
  if (i == 0) data[m] = total;
}

__global__ void k_fill(const int* __restrict__ key, const int* __restrict__ oth, int n,
                       const int* __restrict__ starts, int* __restrict__ cursor,
                       int* __restrict__ out_oth) {
  int i = blockIdx.x * 256 + threadIdx.x;
  if (i >= n) return;
  int k = key[i];
  int pos = starts[k] + atomicAdd(&cursor[k], 1);
  out_oth[pos] = oth[i];
}

// Sort each CSR segment ascending -> deterministic order every replay.
__global__ void k_sort_seg(const int* __restrict__ starts, int nseg,
                           int* __restrict__ vals) {
  int seg = blockIdx.x * 256 + threadIdx.x;
  if (seg >= nseg) return;
  int s = starts[seg], e = starts[seg + 1];
  int d = e - s;
  if (d <= 1) return;
  if (d <= 48) {
    int buf[48];
    for (int i = 0; i < d; i++) buf[i] = vals[s + i];
    for (int i = 1; i < d; i++) {
      int key = buf[i], j = i - 1;
      while (j >= 0 && buf[j] > key) { buf[j + 1] = buf[j]; j--; }
      buf[j + 1] = key;
    }
    for (int i = 0; i < d; i++) vals[s + i] = buf[i];
  } else {
    for (int i = s + 1; i < e; i++) {
      int key = vals[i], j = i - 1;
      while (j >= s && vals[j] > key) { vals[j + 1] = vals[j]; j--; }
      vals[j + 1] = key;
    }
  }
}

// ============================ W2 precompute ============================
__global__ void k_prep_w2g(const float* __restrict__ W2, const float* __restrict__ g2,
                           float* __restrict__ W2g) {
  int i = blockIdx.x * 256 + threadIdx.x;
  if (i >= 256 * 128) return;
  int k = i >> 7;
  W2g[i] = g2[k] * W2[i];
}

__global__ __launch_bounds__(128) void k_prep_sgc0(
    const float* __restrict__ W2, const float* __restrict__ g2,
    const float* __restrict__ b2, const float* __restrict__ bias2,
    float* __restrict__ s_g, float* __restrict__ c0) {
  int t = threadIdx.x;
  float sg = 0.f, cc = 0.f;
  for (int k = 0; k < 256; k++) {
    float w = W2[k * 128 + t];
    sg += g2[k] * w;
    cc += b2[k] * w;
  }
  s_g[t] = sg;
  c0[t] = cc + bias2[t];
}

// ============================ GEMM primitives ============================
// Ash: 32x128 A tile (stride 132). Wsh: 32x64 W chunk (stride 68).
// Thread (tc=t&15, tr=t>>4): rows tr*2..+1, cols tc*4..+3 within a 64-col half.
static __device__ __forceinline__ void stage_w(float (*Wsh)[68], const float* __restrict__ W,
                                               int ldw, int row0, int col0, int t) {
  for (int s = t; s < 512; s += 256) {
    int k = s >> 4, c4 = (s & 15) * 4;
    *(float4*)&Wsh[k][c4] = *(const float4*)(W + (size_t)(row0 + k) * ldw + col0 + c4);
  }
}

static __device__ __forceinline__ void inner32(const float (*Ash)[132], const float (*Wsh)[68],
                                               int kb, int tc, int tr,
                                               float4& acc0, float4& acc1) {
#pragma unroll
  for (int k = 0; k < 32; k += 4) {
    float4 w0 = *(const float4*)&Wsh[k + 0][tc * 4];
    float4 w1 = *(const float4*)&Wsh[k + 1][tc * 4];
    float4 w2 = *(const float4*)&Wsh[k + 2][tc * 4];
    float4 w3 = *(const float4*)&Wsh[k + 3][tc * 4];
    float4 a0 = *(const float4*)&Ash[tr * 2 + 0][kb + k];
    float4 a1 = *(const float4*)&Ash[tr * 2 + 1][kb + k];
    fma4(acc0, a0.x, w0); fma4(acc0, a0.y, w1); fma4(acc0, a0.z, w2); fma4(acc0, a0.w, w3);
    fma4(acc1, a1.x, w0); fma4(acc1, a1.y, w1); fma4(acc1, a1.z, w2); fma4(acc1, a1.w, w3);
  }
}

static __device__ __forceinline__ void load_a128(float (*Ash)[132], const float* __restrict__ A,
                                                 int r0, int N, int t) {
  for (int s = t; s < 1024; s += 256) {
    int r = s >> 5, c4 = (s & 31) * 4;
    float4 val = {0, 0, 0, 0};
    if (r0 + r < N) val = *(const float4*)(A + (size_t)(r0 + r) * 128 + c4);
    *(float4*)&Ash[r][c4] = val;
  }
}

// LN rows of Ash in place (stats optional), 4 waves x 8 rows.
template <bool STATS>
static __device__ __forceinline__ void ln_tile(float (*Ash)[132], const float* __restrict__ g,
                                               const float* __restrict__ b,
                                               float* __restrict__ sn, float* __restrict__ qn,
                                               int r0, int N, int t) {
  int wv = t >> 6, lane = t & 63;
  for (int j = 0; j < 8; j++) {
    int r = wv * 8 + j;
    if (r0 + r < N) {
      float2 x = *(float2*)&Ash[r][lane * 2];
      float s = x.x + x.y, sq = x.x * x.x + x.y * x.y;
      for (int m = 1; m < 64; m <<= 1) { s += __shfl_xor(s, m); sq += __shfl_xor(sq, m); }
      if (STATS && lane == 0) { sn[r0 + r] = s; qn[r0 + r] = sq; }
      float mu = s * (1.f / 128.f);
      float var = sq * (1.f / 128.f) - mu * mu;
      float rstd = rsqrtf(var + LNEPS);
      float2 gg = ((const float2*)g)[lane];
      float2 bb = ((const float2*)b)[lane];
      float2 o;
      o.x = (x.x - mu) * rstd * gg.x + bb.x;
      o.y = (x.y - mu) * rstd * gg.y + bb.y;
      *(float2*)&Ash[r][lane * 2] = o;
    }
  }
}

// ============================ proj + relu + LN-stats + W1 GEMM ============================
// Writes only X0 (the blend anchor); layer-1 consumers read X0 directly.
__global__ __launch_bounds__(256) void k_proj_fused(
    const float* __restrict__ x_in, const float* __restrict__ lin_w,
    const float* __restrict__ lin_b, const float* __restrict__ w1g,
    const float* __restrict__ w1bn, const float* __restrict__ w1w,
    const float* __restrict__ w1b, float* __restrict__ X0,
    float* __restrict__ B, float* __restrict__ sn, float* __restrict__ qn, int N) {
  __shared__ float Ash[32][132];
  __shared__ float Wsh[32][68];
  const int t = threadIdx.x;
  const int r0 = blockIdx.x * 32;
  const int tc = t & 15, tr = t >> 4;
  float4 acc0[2] = {{0,0,0,0},{0,0,0,0}}, acc1[2] = {{0,0,0,0},{0,0,0,0}};
  for (int kq = 0; kq < 4; kq++) {
    __syncthreads();
    for (int s = t; s < 1024; s += 256) {
      int r = s >> 5, c4 = (s & 31) * 4;
      float4 val = {0, 0, 0, 0};
      if (r0 + r < N) val = *(const float4*)(x_in + (size_t)(r0 + r) * 512 + kq * 128 + c4);
      *(float4*)&Ash[r][c4] = val;
    }
    for (int ch = 0; ch < 2; ch++)
      for (int kc = 0; kc < 4; kc++) {
        __syncthreads();
        stage_w(Wsh, lin_w, 128, kq * 128 + kc * 32, ch * 64, t);
        __syncthreads();
        inner32((const float(*)[132])Ash, (const float(*)[68])Wsh, kc * 32, tc, tr,
                acc0[ch], acc1[ch]);
      }
  }
  __syncthreads();
  // relu + write X0, and stash Z into Ash
  for (int ch = 0; ch < 2; ch++) {
    int c = ch * 64 + tc * 4;
    float4 bb = *(const float4*)(lin_b + c);
    int row0 = r0 + tr * 2;
    float4 z0, z1;
    z0.x = fmaxf(acc0[ch].x + bb.x, 0.f); z0.y = fmaxf(acc0[ch].y + bb.y, 0.f);
    z0.z = fmaxf(acc0[ch].z + bb.z, 0.f); z0.w = fmaxf(acc0[ch].w + bb.w, 0.f);
    z1.x = fmaxf(acc1[ch].x + bb.x, 0.f); z1.y = fmaxf(acc1[ch].y + bb.y, 0.f);
    z1.z = fmaxf(acc1[ch].z + bb.z, 0.f); z1.w = fmaxf(acc1[ch].w + bb.w, 0.f);
    if (row0 < N) {
      *(float4*)(X0 + (size_t)row0 * 128 + c) = z0;
      *(float4*)&Ash[tr * 2][c] = z0;
    }
    if (row0 + 1 < N) {
      *(float4*)(X0 + (size_t)(row0 + 1) * 128 + c) = z1;
      *(float4*)&Ash[tr * 2 + 1][c] = z1;
    }
  }
  __syncthreads();
  ln_tile<true>(Ash, w1g, w1bn, sn, qn, r0, N, t);
  // B = LN(Z) @ w1w + w1b
  float4 f0[2] = {{0,0,0,0},{0,0,0,0}}, f1[2] = {{0,0,0,0},{0,0,0,0}};
  for (int ch = 0; ch < 2; ch++)
    for (int kc = 0; kc < 4; kc++) {
      __syncthreads();
      stage_w(Wsh, w1w, 128, kc * 32, ch * 64, t);
      __syncthreads();
      inner32((const float(*)[132])Ash, (const float(*)[68])Wsh, kc * 32, tc, tr,
              f0[ch], f1[ch]);
    }
  for (int ch = 0; ch < 2; ch++) {
    int c = ch * 64 + tc * 4;
    float4 bb = *(const float4*)(w1b + c);
    int row0 = r0 + tr * 2;
    if (row0 < N) {
      float4 o = {f0[ch].x + bb.x, f0[ch].y + bb.y, f0[ch].z + bb.z, f0[ch].w + bb.w};
      *(float4*)(B + (size_t)row0 * 128 + c) = o;
    }
    if (row0 + 1 < N) {
      float4 o = {f1[ch].x + bb.x, f1[ch].y + bb.y, f1[ch].z + bb.z, f1[ch].w + bb.w};
      *(float4*)(B + (size_t)(row0 + 1) * 128 + c) = o;
    }
  }
}

// ============================ hedge mean gather (half-wave per hedge) ============================
__global__ __launch_bounds__(256) void k_xe(
    const float* __restrict__ B, const int* __restrict__ starts,
    const int* __restrict__ vlist, float* __restrict__ Xe,
    float* __restrict__ se, float* __restrict__ qe, int M) {
  int half = threadIdx.x >> 5, lane = threadIdx.x & 31;
  int m = blockIdx.x * 8 + half;
  if (m >= M) return;
  int s = starts[m], e = starts[m + 1];
  float4 acc = {0.f, 0.f, 0.f, 0.f};
  for (int j = s; j < e; j++) {
    int vv = vlist[j];
    float4 val = ((const float4*)(B + (size_t)vv * 128))[lane];
    acc.x += val.x; acc.y += val.y; acc.z += val.z; acc.w += val.w;
  }
  int d = e - s;
  float inv = d > 0 ? 1.f / (float)d : 0.f;
  float4 o = {acc.x * inv, acc.y * inv, acc.z * inv, acc.w * inv};
  ((float4*)(Xe + (size_t)m * 128))[lane] = o;
  float ss = o.x + o.y + o.z + o.w;
  float qq = o.x * o.x + o.y * o.y + o.z * o.z + o.w * o.w;
  for (int mm = 1; mm < 32; mm <<= 1) {
    ss += __shfl_xor(ss, mm, 32);
    qq += __shfl_xor(qq, mm, 32);
  }
  if (lane == 0) { se[m] = ss; qe[m] = qq; }
}

// ============================ node gather (half-wave per node) ============================
__global__ __launch_bounds__(256) void k_nodeg(
    const float* __restrict__ X, const float* __restrict__ Xe,
    const int* __restrict__ starts_v, const int* __restrict__ e_by_v,
    const float* __restrict__ sn, const float* __restrict__ qn,
    const float* __restrict__ se, const float* __restrict__ qe,
    float* __restrict__ P, float* __restrict__ Qb,
    float* __restrict__ invdeg, float* __restrict__ t2arr, int N) {
  int half = threadIdx.x >> 5, lane = threadIdx.x & 31;
  int v = blockIdx.x * 8 + half;
  if (v >= N) return;
  int s = starts_v[v], e = starts_v[v + 1];
  float svn = sn[v], qvn = qn[v];
  float4 acc = {0.f, 0.f, 0.f, 0.f};
  float suma = 0.f, sumb = 0.f;
  for (int j = s; j < e; j++) {
    int ee = e_by_v[j];
    float mu = (svn + se[ee]) * (1.f / 256.f);
    float e2 = (qvn + qe[ee]) * (1.f / 256.f);
    float rstd = rsqrtf(e2 - mu * mu + LNEPS);
    suma += rstd;
    sumb += mu * rstd;
    float4 vv = ((const float4*)(Xe + (size_t)ee * 128))[lane];
    acc.x += rstd * vv.x; acc.y += rstd * vv.y;
    acc.z += rstd * vv.z; acc.w += rstd * vv.w;
  }
  float4 xr = ((const float4*)(X + (size_t)v * 128))[lane];
  float4 pp = {suma * xr.x, suma * xr.y, suma * xr.z, suma * xr.w};
  ((float4*)(P + (size_t)v * 128))[lane] = pp;
  ((float4*)(Qb + (size_t)v * 128))[lane] = acc;
  if (lane == 0) {
    int d = e - s;
    float inv = d > 0 ? 1.f / (float)d : 0.f;
    invdeg[v] = inv;
    t2arr[v] = sumb * inv;
  }
}

// ============================ [P|Q]@W2g + epilogue(blend+LN) ============================
__global__ __launch_bounds__(256) void k_conv2(
    const float* __restrict__ P, const float* __restrict__ Q,
    const float* __restrict__ W, const float* __restrict__ invdeg,
    const float* __restrict__ t2arr, const float* __restrict__ s_g,
    const float* __restrict__ c0, const float* __restrict__ X0,
    const float* __restrict__ wg, const float* __restrict__ wbn,
    float* __restrict__ out, int N) {
  __shared__ float Ash[32][132];
  __shared__ float Wsh[32][68];
  const int t = threadIdx.x;
  const int r0 = blockIdx.x * 32;
  const int tc = t & 15, tr = t >> 4;
  float4 acc0[2] = {{0,0,0,0},{0,0,0,0}}, acc1[2] = {{0,0,0,0},{0,0,0,0}};
  for (int ph = 0; ph < 2; ph++) {
    __syncthreads();
    load_a128(Ash, ph ? Q : P, r0, N, t);
    for (int ch = 0; ch < 2; ch++)
      for (int kc = 0; kc < 4; kc++) {
        __syncthreads();
        stage_w(Wsh, W, 128, ph * 128 + kc * 32, ch * 64, t);
        __syncthreads();
        inner32((const float(*)[132])Ash, (const float(*)[68])Wsh, kc * 32, tc, tr,
                acc0[ch], acc1[ch]);
      }
  }
  __syncthreads();
  // epilogue: Xv = G*invdeg - t2*s_g + flag*c0; blend with X0 -> Ash
  for (int r = 0; r < 2; r++) {
    int row = r0 + tr * 2 + r;
    if (row < N) {
      float t1 = invdeg[row], t2 = t2arr[row];
      float flag = t1 > 0.f ? 1.f : 0.f;
      for (int ch = 0; ch < 2; ch++) {
        int c = ch * 64 + tc * 4;
        float4 g = r ? acc1[ch] : acc0[ch];
        float4 sg = *(const float4*)(s_g + c);
        float4 cc = *(const float4*)(c0 + c);
        float4 x0 = *(const float4*)(X0 + (size_t)row * 128 + c);
        float4 z;
        z.x = 0.5f * (g.x * t1 - t2 * sg.x + flag * cc.x) + 0.5f * x0.x;
        z.y = 0.5f * (g.y * t1 - t2 * sg.y + flag * cc.y) + 0.5f * x0.y;
        z.z = 0.5f * (g.z * t1 - t2 * sg.z + flag * cc.z) + 0.5f * x0.z;
        z.w = 0.5f * (g.w * t1 - t2 * sg.w + flag * cc.w) + 0.5f * x0.w;
        *(float4*)&Ash[tr * 2 + r][c] = z;
      }
    }
  }
  __syncthreads();
  // LN -> out
  int wv = t >> 6, lane = t & 63;
  for (int j = 0; j < 8; j++) {
    int r = wv * 8 + j;
    if (r0 + r < N) {
      float2 x = *(float2*)&Ash[r][lane * 2];
      float s = x.x + x.y, sq = x.x * x.x + x.y * x.y;
      for (int m = 1; m < 64; m <<= 1) { s += __shfl_xor(s, m); sq += __shfl_xor(sq, m); }
      float mu = s * (1.f / 128.f);
      float var = sq * (1.f / 128.f) - mu * mu;
      float rstd = rsqrtf(var + LNEPS);
      float2 gg = ((const float2*)wg)[lane];
      float2 bb = ((const float2*)wbn)[lane];
      float2 o;
      o.x = (x.x - mu) * rstd * gg.x + bb.x;
      o.y = (x.y - mu) * rstd * gg.y + bb.y;
      *(float2*)(out + (size_t)(r0 + r) * 128 + lane * 2) = o;
    }
  }
}

// ============================ W-GEMM+relu -> X ; LN-stats ; W1 GEMM -> B ============================
__global__ __launch_bounds__(256) void k_wnext(
    const float* __restrict__ Xin, const float* __restrict__ Ww,
    const float* __restrict__ wb, const float* __restrict__ w1g,
    const float* __restrict__ w1bn, const float* __restrict__ w1w,
    const float* __restrict__ w1b, float* __restrict__ Xout,
    float* __restrict__ B, float* __restrict__ sn, float* __restrict__ qn, int N) {
  __shared__ float Ash[32][132];
  __shared__ float Wsh[32][68];
  const int t = threadIdx.x;
  const int r0 = blockIdx.x * 32;
  const int tc = t & 15, tr = t >> 4;
  load_a128(Ash, Xin, r0, N, t);
  float4 acc0[2] = {{0,0,0,0},{0,0,0,0}}, acc1[2] = {{0,0,0,0},{0,0,0,0}};
  for (int ch = 0; ch < 2; ch++)
    for (int kc = 0; kc < 4; kc++) {
      __syncthreads();
      stage_w(Wsh, Ww, 128, kc * 32, ch * 64, t);
      __syncthreads();
      inner32((const float(*)[132])Ash, (const float(*)[68])Wsh, kc * 32, tc, tr,
              acc0[ch], acc1[ch]);
    }
  __syncthreads();
  for (int ch = 0; ch < 2; ch++) {
    int c = ch * 64 + tc * 4;
    float4 bb = *(const float4*)(wb + c);
    int row0 = r0 + tr * 2;
    float4 z0, z1;
    z0.x = fmaxf(acc0[ch].x + bb.x, 0.f); z0.y = fmaxf(acc0[ch].y + bb.y, 0.f);
    z0.z = fmaxf(acc0[ch].z + bb.z, 0.f); z0.w = fmaxf(acc0[ch].w + bb.w, 0.f);
    z1.x = fmaxf(acc1[ch].x + bb.x, 0.f); z1.y = fmaxf(acc1[ch].y + bb.y, 0.f);
    z1.z = fmaxf(acc1[ch].z + bb.z, 0.f); z1.w = fmaxf(acc1[ch].w + bb.w, 0.f);
    if (row0 < N) {
      *(float4*)(Xout + (size_t)row0 * 128 + c) = z0;
      *(float4*)&Ash[tr * 2][c] = z0;
    }
    if (row0 + 1 < N) {
      *(float4*)(Xout + (size_t)(row0 + 1) * 128 + c) = z1;
      *(float4*)&Ash[tr * 2 + 1][c] = z1;
    }
  }
  __syncthreads();
  ln_tile<true>(Ash, w1g, w1bn, sn, qn, r0, N, t);
  float4 f0[2] = {{0,0,0,0},{0,0,0,0}}, f1[2] = {{0,0,0,0},{0,0,0,0}};
  for (int ch = 0; ch < 2; ch++)
    for (int kc = 0; kc < 4; kc++) {
      __syncthreads();
      stage_w(Wsh, w1w, 128, kc * 32, ch * 64, t);
      __syncthreads();
      inner32((const float(*)[132])Ash, (const float(*)[68])Wsh, kc * 32, tc, tr,
              f0[ch], f1[ch]);
    }
  for (int ch = 0; ch < 2; ch++) {
    int c = ch * 64 + tc * 4;
    float4 bb = *(const float4*)(w1b + c);
    int row0 = r0 + tr * 2;
    if (row0 < N) {
      float4 o = {f0[ch].x + bb.x, f0[ch].y + bb.y, f0[ch].z + bb.z, f0[ch].w + bb.w};
      *(float4*)(B + (size_t)row0 * 128 + c) = o;
    }
    if (row0 + 1 < N) {
      float4 o = {f1[ch].x + bb.x, f1[ch].y + bb.y, f1[ch].z + bb.z, f1[ch].w + bb.w};
      *(float4*)(B + (size_t)(row0 + 1) * 128 + c) = o;
    }
  }
}

// ============================ W-GEMM+relu ; classifier (cw1 GEMM, LN64, dot) ============================
__global__ __launch_bounds__(256) void k_wcls(
    const float* __restrict__ Xin, const float* __restrict__ Ww,
    const float* __restrict__ wb, const float* __restrict__ cw1,
    const float* __restrict__ cb1, const float* __restrict__ cg,
    const float* __restrict__ cbn, const float* __restrict__ cw2,
    const float* __restrict__ cb2, float* __restrict__ out, int N) {
  __shared__ float Ash[32][132];
  __shared__ float Wsh[32][68];
  const int t = threadIdx.x;
  const int r0 = blockIdx.x * 32;
  const int tc = t & 15, tr = t >> 4;
  load_a128(Ash, Xin, r0, N, t);
  float4 acc0[2] = {{0,0,0,0},{0,0,0,0}}, acc1[2] = {{0,0,0,0},{0,0,0,0}};
  for (int ch = 0; ch < 2; ch++)
    for (int kc = 0; kc < 4; kc++) {
      __syncthreads();
      stage_w(Wsh, Ww, 128, kc * 32, ch * 64, t);
      __syncthreads();
      inner32((const float(*)[132])Ash, (const float(*)[68])Wsh, kc * 32, tc, tr,
              acc0[ch], acc1[ch]);
    }
  __syncthreads();
  for (int ch = 0; ch < 2; ch++) {
    int c = ch * 64 + tc * 4;
    float4 bb = *(const float4*)(wb + c);
    int row0 = r0 + tr * 2;
    if (row0 < N) {
      float4 z;
      z.x = fmaxf(acc0[ch].x + bb.x, 0.f); z.y = fmaxf(acc0[ch].y + bb.y, 0.f);
      z.z = fmaxf(acc0[ch].z + bb.z, 0.f); z.w = fmaxf(acc0[ch].w + bb.w, 0.f);
      *(float4*)&Ash[tr * 2][c] = z;
    }
    if (row0 + 1 < N) {
      float4 z;
      z.x = fmaxf(acc1[ch].x + bb.x, 0.f); z.y = fmaxf(acc1[ch].y + bb.y, 0.f);
      z.z = fmaxf(acc1[ch].z + bb.z, 0.f); z.w = fmaxf(acc1[ch].w + bb.w, 0.f);
      *(float4*)&Ash[tr * 2 + 1][c] = z;
    }
  }
  // H = relu(Z @ cw1 + cb1): 64 cols
  float4 h0 = {0,0,0,0}, h1 = {0,0,0,0};
  for (int kc = 0; kc < 4; kc++) {
    __syncthreads();
    stage_w(Wsh, cw1, 64, kc * 32, 0, t);
    __syncthreads();
    inner32((const float(*)[132])Ash, (const float(*)[68])Wsh, kc * 32, tc, tr, h0, h1);
  }
  __syncthreads();
  {
    int c = tc * 4;
    float4 bb = *(const float4*)(cb1 + c);
    float4 z;
    z.x = fmaxf(h0.x + bb.x, 0.f); z.y = fmaxf(h0.y + bb.y, 0.f);
    z.z = fmaxf(h0.z + bb.z, 0.f); z.w = fmaxf(h0.w + bb.w, 0.f);
    *(float4*)&Wsh[tr * 2][c] = z;
    z.x = fmaxf(h1.x + bb.x, 0.f); z.y = fmaxf(h1.y + bb.y, 0.f);
    z.z = fmaxf(h1.z + bb.z, 0.f); z.w = fmaxf(h1.w + bb.w, 0.f);
    *(float4*)&Wsh[tr * 2 + 1][c] = z;
  }
  __syncthreads();
  // LN(64) + dot(cw2) per row; 4 waves x 8 rows, 64 lanes = 64 cols
  int wv = t >> 6, lane = t & 63;
  for (int j = 0; j < 8; j++) {
    int r = wv * 8 + j;
    if (r0 + r < N) {
      float h = Wsh[r][lane];
      float s = h, sq = h * h;
      for (int m = 1; m < 64; m <<= 1) { s += __shfl_xor(s, m); sq += __shfl_xor(sq, m); }
      float mu = s * (1.f / 64.f);
      float var = sq * (1.f / 64.f) - mu * mu;
      float rstd = rsqrtf(var + LNEPS);
      float hn = (h - mu) * rstd * cg[lane] + cbn[lane];
      float c = hn * cw2[lane];
      for (int m = 1; m < 64; m <<= 1) c += __shfl_xor(c, m);
      if (lane == 0) out[r0 + r] = c + cb2[0];
    }
  }
}

// ============================ driver ============================
static void run_branch(const float* x_in, const int* v, const int* e,
                       const float* lin_w, const float* lin_b,
                       const float* w1g, const float* w1bn, const float* w1w, const float* w1b,
                       const float* W2g, const float* s_g, const float* c0,
                       const float* wg, const float* wbn, const float* ww, const float* wb,
                       const float* cw1, const float* cb1, const float* cg, const float* cbn,
                       const float* cw2, const float* cb2,
                       float* X, float* X0, float* B, float* Qb, float* Xe,
                       float* sn, float* qn, float* se, float* qe,
                       float* invdeg, float* t2arr,
                       int* starts_e, int* starts_v, int* cursor, int* bsums,
                       int* v_by_e, int* e_by_v,
                       float* out, hipStream_t stream) {
  const int GN = (NN + 31) / 32;
  // CSR by hedge
  hipMemsetAsync(starts_e, 0, (NH + 1) * sizeof(int), stream);
  k_hist<<<(NI + 255) / 256, 256, 0, stream>>>(e, NI, starts_e);
  k_scan1<<<(NH + 1023) / 1024, 1024, 0, stream>>>(starts_e, NH, bsums);
  k_scan2<<<1, 1024, 0, stream>>>(bsums, (NH + 1023) / 1024);
  k_scan3<<<(NH + 255) / 256, 256, 0, stream>>>(starts_e, bsums, NH, NI);
  hipMemsetAsync(cursor, 0, NH * sizeof(int), stream);
  k_fill<<<(NI + 255) / 256, 256, 0, stream>>>(e, v, NI, starts_e, cursor, v_by_e);
  k_sort_seg<<<(NH + 255) / 256, 256, 0, stream>>>(starts_e, NH, v_by_e);
  // CSR by node
  hipMemsetAsync(starts_v, 0, (NN + 1) * sizeof(int), stream);
  k_hist<<<(NI + 255) / 256, 256, 0, stream>>>(v, NI, starts_v);
  k_scan1<<<(NN + 1023) / 1024, 1024, 0, stream>>>(starts_v, NN, bsums);
  k_scan2<<<1, 1024, 0, stream>>>(bsums, (NN + 1023) / 1024);
  k_scan3<<<(NN + 255) / 256, 256, 0, stream>>>(starts_v, bsums, NN, NI);
  hipMemsetAsync(cursor, 0, NN * sizeof(int), stream);
  k_fill<<<(NI + 255) / 256, 256, 0, stream>>>(v, e, NI, starts_v, cursor, e_by_v);
  k_sort_seg<<<(NN + 255) / 256, 256, 0, stream>>>(starts_v, NN, e_by_v);
  // proj + relu -> X0 ; LN-stats -> sn,qn ; W1 GEMM -> B   (X first written by k_conv2)
  k_proj_fused<<<GN, 256, 0, stream>>>(x_in, lin_w, lin_b, w1g, w1bn, w1w, w1b,
                                       X0, B, sn, qn, NN);
  for (int layer = 0; layer < 2; ++layer) {
    k_xe<<<NH / 8, 256, 0, stream>>>(B, starts_e, v_by_e, Xe, se, qe, NH);
    k_nodeg<<<(NN + 7) / 8, 256, 0, stream>>>(layer == 0 ? X0 : X, Xe, starts_v,
                                              e_by_v, sn, qn, se, qe, B, Qb,
                                              invdeg, t2arr, NN);
    k_conv2<<<GN, 256, 0, stream>>>(B, Qb, W2g, invdeg, t2arr, s_g, c0, X0,
                                    wg, wbn, X, NN);
    if (layer == 0) {
      k_wnext<<<GN, 256, 0, stream>>>(X, ww, wb, w1g, w1bn, w1w, w1b,
                                      X, B, sn, qn, NN);
    } else {
      k_wcls<<<GN, 256, 0, stream>>>(X, ww, wb, cw1, cb1, cg, cbn, cw2, cb2,
                                     out, NN);
    }
  }
}

extern "C" void kernel_launch(void* const* d_in, const int* in_sizes, int n_in,
                              void* d_out, int out_size, void* d_ws, size_t ws_size,
                              hipStream_t stream) {
  (void)in_sizes; (void)n_in; (void)out_size; (void)ws_size;
  const float* x1 = (const float*)d_in[0];
  const int* v1 = (const int*)d_in[1];
  const int* e1 = (const int*)d_in[2];
  const float* x2 = (const float*)d_in[3];
  const int* v2 = (const int*)d_in[4];
  const int* e2 = (const int*)d_in[5];
  const float* lin_w = (const float*)d_in[6];
  const float* lin_b = (const float*)d_in[7];
  const float* w1g = (const float*)d_in[8];
  const float* w1bn = (const float*)d_in[9];
  const float* w1w = (const float*)d_in[10];
  const float* w1b = (const float*)d_in[11];
  const float* w2g = (const float*)d_in[12];
  const float* w2bn = (const float*)d_in[13];
  const float* w2w = (const float*)d_in[14];
  const float* w2b = (const float*)d_in[15];
  const float* wg = (const float*)d_in[16];
  const float* wbn = (const float*)d_in[17];
  const float* ww = (const float*)d_in[18];
  const float* wb = (const float*)d_in[19];
  const float* cw1 = (const float*)d_in[20];
  const float* cb1 = (const float*)d_in[21];
  const float* cg = (const float*)d_in[22];
  const float* cbn = (const float*)d_in[23];
  const float* cw2 = (const float*)d_in[24];
  const float* cb2 = (const float*)d_in[25];

  char* p = (char*)d_ws;
  auto alloc = [&](size_t bytes) {
    char* r = p;
    p += (bytes + 255) & ~(size_t)255;
    return r;
  };
  float* X = (float*)alloc((size_t)NN * 128 * 4);
  float* X0 = (float*)alloc((size_t)NN * 128 * 4);
  float* B = (float*)alloc((size_t)NN * 128 * 4);
  float* Qb = (float*)alloc((size_t)NN * 128 * 4);
  float* Xe = (float*)alloc((size_t)NH * 128 * 4);
  float* sn = (float*)alloc((size_t)NN * 4);
  float* qn = (float*)alloc((size_t)NN * 4);
  float* se = (float*)alloc((size_t)NH * 4);
  float* qe = (float*)alloc((size_t)NH * 4);
  float* invdeg = (float*)alloc((size_t)NN * 4);
  float* t2arr = (float*)alloc((size_t)NN * 4);
  int* starts_e = (int*)alloc((NH + 1) * 4);
  int* starts_v = (int*)alloc((NN + 1) * 4);
  int* cursor = (int*)alloc(NH * 4);
  int* bsums = (int*)alloc(1024 * 4);
  int* v_by_e = (int*)alloc((size_t)NI * 4);
  int* e_by_v = (int*)alloc((size_t)NI * 4);
  float* W2g = (float*)alloc((size_t)256 * 128 * 4);
  float* s_g = (float*)alloc(128 * 4);
  float* c0 = (float*)alloc(128 * 4);

  // one-time per launch: W2 precomputation (shared by both branches)
  k_prep_w2g<<<128, 256, 0, stream>>>(w2w, w2g, W2g);
  k_prep_sgc0<<<1, 128, 0, stream>>>(w2w, w2g, w2bn, w2b, s_g, c0);

  float* out = (float*)d_out;
  run_branch(x1, v1, e1, lin_w, lin_b, w1g, w1bn, w1w, w1b, W2g, s_g, c0,
             wg, wbn, ww, wb, cw1, cb1, cg, cbn, cw2, cb2,
             X, X0, B, Qb, Xe, sn, qn, se, qe, invdeg, t2arr,
             starts_e, starts_v, cursor, bsums, v_by_e, e_by_v, out, stream);
  run_branch(x2, v2, e2, lin_w, lin_b, w1g, w1bn, w1w, w1b, W2g, s_g, c0,
             wg, wbn, ww, wb, cw1, cb1, cg, cbn, cw2, cb2,
             X, X0, B, Qb, Xe, sn, qn, se, qe, invdeg, t2arr,
             starts_e, starts_v, cursor, bsums, v_by_e, e_by_v, out + NN, stream);
}